// Round 5
// baseline (174.801 us; speedup 1.0000x reference)
//
#include <hip/hip_runtime.h>

// InfiniAttn forward on gfx950.
// cvt h->bf16 | transpose W->bf16 | GEMM qkv | fused flash attn + mem-gate
// (split-KV 8-wave blocks, fixed-max softmax => partials combine by pure sum,
// prescaled Q, swizzled LDS, double-buffered async staging) | GEMM out 64x128 | +h,LN.

typedef unsigned short ushort_t;
typedef unsigned int uint32;

typedef __bf16 bf16x8 __attribute__((ext_vector_type(8)));
typedef float f32x4 __attribute__((ext_vector_type(4)));
typedef float f32x16 __attribute__((ext_vector_type(16)));
typedef unsigned short u16x8 __attribute__((ext_vector_type(8)));
typedef unsigned short u16x4 __attribute__((ext_vector_type(4)));
typedef unsigned int u32x4 __attribute__((ext_vector_type(4)));

typedef const __attribute__((address_space(1))) void gvoid_t;
typedef __attribute__((address_space(3))) void lvoid_t;

#define S_LEN 2048
#define BATCH 2
#define NHEAD 16

__device__ __forceinline__ ushort_t f2bf(float x) {
  union { float f; unsigned u; } c; c.f = x;
  unsigned r = (c.u + 0x7FFFu + ((c.u >> 16) & 1u)) >> 16;
  return (ushort_t)r;
}
__device__ __forceinline__ float bf2f(ushort_t v) {
  union { unsigned u; float f; } c; c.u = ((unsigned)v) << 16;
  return c.f;
}

// ---------------- dtype convert: h (fp32) -> bf16 ----------------
__global__ __launch_bounds__(256) void k_cvt_h(const float* __restrict__ src,
                                               ushort_t* __restrict__ dst, int n4) {
  int idx = blockIdx.x * 256 + threadIdx.x;
  if (idx >= n4) return;
  float4 v = ((const float4*)src)[idx];
  u16x4 o; o[0] = f2bf(v.x); o[1] = f2bf(v.y); o[2] = f2bf(v.z); o[3] = f2bf(v.w);
  ((u16x4*)dst)[idx] = o;
}

// ------------- transpose-convert: W[K][N] fp32 -> WT[N][K] bf16 -------------
__global__ __launch_bounds__(256) void k_cvt_wT(const float* __restrict__ W,
                                                ushort_t* __restrict__ WT, int K, int N) {
  __shared__ float tile[32][33];
  const int n0 = blockIdx.x * 32, k0 = blockIdx.y * 32;
  const int tx = threadIdx.x & 31, ty = threadIdx.x >> 5;
#pragma unroll
  for (int r = 0; r < 32; r += 8)
    tile[ty + r][tx] = W[(size_t)(k0 + ty + r) * N + n0 + tx];
  __syncthreads();
#pragma unroll
  for (int r = 0; r < 32; r += 8)
    WT[(size_t)(n0 + ty + r) * K + k0 + tx] = f2bf(tile[tx][ty + r]);
}

// ------------- GEMM 128x128: C = A[M][K](bf16) * B[N][K]^T(bf16), m97-style + XCD swizzle -------------
template <int OUT_BF16>
__global__ __launch_bounds__(256) void k_gemm_bt(const ushort_t* __restrict__ A,
                                                 const ushort_t* __restrict__ B,
                                                 void* __restrict__ Cv, int M, int N, int K,
                                                 int nbx) {
  __shared__ __attribute__((aligned(16))) ushort_t As[128 * 32];
  __shared__ __attribute__((aligned(16))) ushort_t Bs[128 * 32];
  const int per = gridDim.x >> 3;  // grid % 8 == 0
  const int fl = (blockIdx.x & 7) * per + (blockIdx.x >> 3);
  const int m0 = (fl / nbx) * 128, n0 = (fl % nbx) * 128;
  const int tid = threadIdx.x, w = tid >> 6, lane = tid & 63;
  const int wm = (w >> 1) * 64, wn = (w & 1) * 64;
  const int l15 = lane & 15, l4 = lane >> 4;
  f32x4 acc[4][4];
#pragma unroll
  for (int i = 0; i < 4; ++i)
#pragma unroll
    for (int j = 0; j < 4; ++j)
#pragma unroll
      for (int r = 0; r < 4; ++r) acc[i][j][r] = 0.f;

  for (int k0 = 0; k0 < K; k0 += 32) {
    __syncthreads();
#pragma unroll
    for (int r = 0; r < 2; ++r) {
      int c = r * 256 + w * 64 + lane;
      const ushort_t* ga = A + (size_t)(m0 + (c >> 2)) * K + k0 + (c & 3) * 8;
      const ushort_t* gb = B + (size_t)(n0 + (c >> 2)) * K + k0 + (c & 3) * 8;
      __builtin_amdgcn_global_load_lds((gvoid_t*)ga, (lvoid_t*)(As + (r * 256 + w * 64) * 8), 16, 0, 0);
      __builtin_amdgcn_global_load_lds((gvoid_t*)gb, (lvoid_t*)(Bs + (r * 256 + w * 64) * 8), 16, 0, 0);
    }
    __syncthreads();
    bf16x8 af[4], bfr[4];
#pragma unroll
    for (int i = 0; i < 4; ++i) af[i] = *(const bf16x8*)&As[(wm + i * 16 + l15) * 32 + l4 * 8];
#pragma unroll
    for (int j = 0; j < 4; ++j) bfr[j] = *(const bf16x8*)&Bs[(wn + j * 16 + l15) * 32 + l4 * 8];
#pragma unroll
    for (int i = 0; i < 4; ++i)
#pragma unroll
      for (int j = 0; j < 4; ++j)
        acc[i][j] = __builtin_amdgcn_mfma_f32_16x16x32_bf16(af[i], bfr[j], acc[i][j], 0, 0, 0);
  }
#pragma unroll
  for (int i = 0; i < 4; ++i)
#pragma unroll
    for (int j = 0; j < 4; ++j)
#pragma unroll
      for (int r = 0; r < 4; ++r) {
        int row = m0 + wm + i * 16 + l4 * 4 + r;
        int col = n0 + wn + j * 16 + l15;
        if (OUT_BF16)
          ((ushort_t*)Cv)[(size_t)row * N + col] = f2bf(acc[i][j][r]);
        else
          ((float*)Cv)[(size_t)row * N + col] = acc[i][j][r];
      }
}

// ------------- GEMM 64x128 tiles (for M=4096,N=1024: 512 blocks = 2/CU) -------------
__global__ __launch_bounds__(256) void k_gemm64(const ushort_t* __restrict__ A,
                                                const ushort_t* __restrict__ B,
                                                float* __restrict__ C, int M, int N, int K,
                                                int nbx) {
  __shared__ __attribute__((aligned(16))) ushort_t As[64 * 32];
  __shared__ __attribute__((aligned(16))) ushort_t Bs[128 * 32];
  const int per = gridDim.x >> 3;
  const int fl = (blockIdx.x & 7) * per + (blockIdx.x >> 3);
  const int m0 = (fl / nbx) * 64, n0 = (fl % nbx) * 128;
  const int tid = threadIdx.x, w = tid >> 6, lane = tid & 63;
  const int wn = w * 32;
  const int l15 = lane & 15, l4 = lane >> 4;
  f32x4 acc[4][2];
#pragma unroll
  for (int i = 0; i < 4; ++i)
#pragma unroll
    for (int j = 0; j < 2; ++j)
#pragma unroll
      for (int r = 0; r < 4; ++r) acc[i][j][r] = 0.f;

  for (int k0 = 0; k0 < K; k0 += 32) {
    __syncthreads();
    {
      int c = w * 64 + lane;
      const ushort_t* ga = A + (size_t)(m0 + (c >> 2)) * K + k0 + (c & 3) * 8;
      __builtin_amdgcn_global_load_lds((gvoid_t*)ga, (lvoid_t*)(As + w * 512), 16, 0, 0);
#pragma unroll
      for (int r = 0; r < 2; ++r) {
        int c2 = r * 256 + w * 64 + lane;
        const ushort_t* gb = B + (size_t)(n0 + (c2 >> 2)) * K + k0 + (c2 & 3) * 8;
        __builtin_amdgcn_global_load_lds((gvoid_t*)gb, (lvoid_t*)(Bs + r * 2048 + w * 512), 16, 0, 0);
      }
    }
    __syncthreads();
    bf16x8 af[4], bfr[2];
#pragma unroll
    for (int i = 0; i < 4; ++i) af[i] = *(const bf16x8*)&As[(i * 16 + l15) * 32 + l4 * 8];
#pragma unroll
    for (int j = 0; j < 2; ++j) bfr[j] = *(const bf16x8*)&Bs[(wn + j * 16 + l15) * 32 + l4 * 8];
#pragma unroll
    for (int i = 0; i < 4; ++i)
#pragma unroll
      for (int j = 0; j < 2; ++j)
        acc[i][j] = __builtin_amdgcn_mfma_f32_16x16x32_bf16(af[i], bfr[j], acc[i][j], 0, 0, 0);
  }
#pragma unroll
  for (int i = 0; i < 4; ++i)
#pragma unroll
    for (int j = 0; j < 2; ++j)
#pragma unroll
      for (int r = 0; r < 4; ++r)
        C[(size_t)(m0 + i * 16 + l4 * 4 + r) * N + n0 + wn + j * 16 + l15] = acc[i][j][r];
}

// ------------- K staging: global_load_lds with pre-swizzled source -------------
// K LDS layout [64 rows][64 shorts], read swizzle: slot ^= (row & 7).
__device__ __forceinline__ void stage_k(const ushort_t* __restrict__ qkv, ushort_t* kw,
                                        int j0, int b, int n, int w, int lane) {
#pragma unroll
  for (int r = 0; r < 2; ++r) {
    int jb_ = w * 16 + r * 8;  // multiple of 8 -> (row&7) == lane>>3
    const ushort_t* ksrc = qkv + (size_t)(j0 + jb_ + (lane >> 3)) * 6144 + b * 3072 + n * 64 + 1024
                           + (((lane & 7) ^ (lane >> 3)) << 3);
    __builtin_amdgcn_global_load_lds((gvoid_t*)ksrc, (lvoid_t*)(kw + jb_ * 64), 16, 0, 0);
  }
}

// ------------- fused flash attention + memory gate (split-KV, 8 waves, fixed-max) -------------
// Fixed-max softmax: scores analytically bounded; P = exp(s), l = sum P.
// Halves combine by PURE SUMMATION of (O, l) through LDS.
// smem carve (64KB): K[hh][buf] at (hh*2+buf)*4096 shorts; VT[hh][buf] at 16384 + same.
// Exchange reuses [0,32KB) as fp32 O-partials, [32KB,33KB) as l.
__global__ __launch_bounds__(512, 4) void k_attn(const ushort_t* __restrict__ qkv,
                                                 const float* __restrict__ mem,
                                                 const float* __restrict__ mnorm,
                                                 const float* __restrict__ gbeta,
                                                 ushort_t* __restrict__ inj) {
  __shared__ __attribute__((aligned(16))) ushort_t smem[32768];
  const int bn = blockIdx.y, b = bn & 1, n = bn >> 1;
  const int tid = threadIdx.x;
  const int hh = tid >> 8;           // KV half
  const int ht = tid & 255;          // thread within half
  const int w4 = (tid >> 6) & 3, lane = tid & 63;
  const int l31 = lane & 31, h = lane >> 5;
  const int qrow = blockIdx.x * 128 + w4 * 32 + l31;
  const size_t qoff = (size_t)qrow * 6144 + b * 3072 + n * 64;
  const float CEXP = 0.18033688011113723f;  // 0.125 * log2(e)
  // prescaled Q fragments (fold scale*log2e into Q: exp2(sv) == e^(q.k/8))
  bf16x8 qf[4];
#pragma unroll
  for (int ks = 0; ks < 4; ++ks) {
    u16x8 qv = *(const u16x8*)(qkv + qoff + ks * 16 + h * 8);
    union { u16x8 u; bf16x8 v; } cu;
#pragma unroll
    for (int e = 0; e < 8; ++e) cu.u[e] = f2bf(bf2f(qv[e]) * CEXP);
    qf[ks] = cu.v;
  }

  const int vj = ht >> 2, vdq = (ht & 3) * 16, a2 = (ht & 3) * 2;
  const size_t vbase = (size_t)b * 3072 + n * 64 + 2048 + vdq;
  const int krd = l31 & 7;
  const int fv0 = (l31 & 7) ^ (l31 >> 3);
  const int fv1 = fv0 ^ 4;
  const int tile0 = hh * 16;  // this half's first KV tile

  // ---- prologue: stage this half's tile 0 ----
  stage_k(qkv, smem + hh * 8192, tile0 * 64, b, n, w4, lane);
  {
    const ushort_t* vsrc = qkv + (size_t)(tile0 * 64 + vj) * 6144 + vbase;
    u16x8 vr0 = *(const u16x8*)vsrc;
    u16x8 vr1 = *(const u16x8*)(vsrc + 8);
    ushort_t* Vw = smem + 16384 + hh * 8192;
#pragma unroll
    for (int e = 0; e < 8; ++e) {
      int f0 = (e ^ a2) << 3;
      Vw[(vdq + e) * 64 + (vj ^ f0)] = vr0[e];
      Vw[(vdq + 8 + e) * 64 + (vj ^ f0 ^ 8)] = vr1[e];
    }
  }
  __syncthreads();

  f32x16 oacc[2];
#pragma unroll
  for (int r = 0; r < 16; ++r) { oacc[0][r] = 0.f; oacc[1][r] = 0.f; }
  float l_run = 0.f;

  for (int t = 0; t < 16; ++t) {
    const int bb = t & 1;
    const ushort_t* Kb = smem + (hh * 2 + bb) * 4096;
    const ushort_t* Vb = smem + 16384 + (hh * 2 + bb) * 4096;
    u16x8 nv0, nv1;
    if (t < 15) {  // async prefetch of this half's tile t+1
      stage_k(qkv, smem + (hh * 2 + (bb ^ 1)) * 4096, (tile0 + t + 1) * 64, b, n, w4, lane);
      const ushort_t* vsrc = qkv + (size_t)((tile0 + t + 1) * 64 + vj) * 6144 + vbase;
      nv0 = *(const u16x8*)vsrc;
      nv1 = *(const u16x8*)(vsrc + 8);
    }
    // S^T = mfma(A=K, B=Q): lane holds S[own q=l31][j = jb*32 + (r&3)+8*(r>>2)+4h]
    f32x16 sv[2];
#pragma unroll
    for (int r = 0; r < 16; ++r) { sv[0][r] = 0.f; sv[1][r] = 0.f; }
    __builtin_amdgcn_s_setprio(1);
#pragma unroll
    for (int jb = 0; jb < 2; ++jb) {
      const int rb = (jb * 32 + l31) * 64;
#pragma unroll
      for (int ks = 0; ks < 4; ++ks) {
        bf16x8 kf = *(const bf16x8*)&Kb[rb + ((((ks << 1) | h) ^ krd) << 3)];
        sv[jb] = __builtin_amdgcn_mfma_f32_32x32x16_bf16(kf, qf[ks], sv[jb], 0, 0, 0);
      }
    }
    __builtin_amdgcn_s_setprio(0);
    // fixed-max softmax: p = exp2(sv) in place (Q prescaled); no max tree, no rescale
#pragma unroll
    for (int jb = 0; jb < 2; ++jb)
#pragma unroll
      for (int r = 0; r < 16; ++r)
        sv[jb][r] = __builtin_amdgcn_exp2f(sv[jb][r]);
    // PV: O^T = mfma(A=V^T, B=P^T); P-frags via cvt_pk + permlane32_swap (T12)
#pragma unroll
    for (int ks = 0; ks < 4; ++ks) {
      const int jb = ks >> 1, q0 = (ks & 1) * 2;
      uint32 X0, X1, Y0, Y1;
      asm volatile("v_cvt_pk_bf16_f32 %0, %1, %2" : "=v"(X0) : "v"(sv[jb][q0 * 4 + 0]), "v"(sv[jb][q0 * 4 + 1]));
      asm volatile("v_cvt_pk_bf16_f32 %0, %1, %2" : "=v"(X1) : "v"(sv[jb][q0 * 4 + 2]), "v"(sv[jb][q0 * 4 + 3]));
      asm volatile("v_cvt_pk_bf16_f32 %0, %1, %2" : "=v"(Y0) : "v"(sv[jb][(q0 + 1) * 4 + 0]), "v"(sv[jb][(q0 + 1) * 4 + 1]));
      asm volatile("v_cvt_pk_bf16_f32 %0, %1, %2" : "=v"(Y1) : "v"(sv[jb][(q0 + 1) * 4 + 2]), "v"(sv[jb][(q0 + 1) * 4 + 3]));
      asm volatile("v_permlane32_swap_b32 %0, %1" : "+v"(X0), "+v"(Y0));
      asm volatile("v_permlane32_swap_b32 %0, %1" : "+v"(X1), "+v"(Y1));
      union { u32x4 u; bf16x8 v; } pf;
      pf.u[0] = X0; pf.u[1] = X1; pf.u[2] = Y0; pf.u[3] = Y1;
      bf16x8 vf0 = *(const bf16x8*)&Vb[l31 * 64 + ((((ks << 1) | h) ^ fv0) << 3)];
      bf16x8 vf1 = *(const bf16x8*)&Vb[(32 + l31) * 64 + ((((ks << 1) | h) ^ fv1) << 3)];
      __builtin_amdgcn_s_setprio(1);
      oacc[0] = __builtin_amdgcn_mfma_f32_32x32x16_bf16(vf0, pf.v, oacc[0], 0, 0, 0);
      oacc[1] = __builtin_amdgcn_mfma_f32_32x32x16_bf16(vf1, pf.v, oacc[1], 0, 0, 0);
      __builtin_amdgcn_s_setprio(0);
    }
    // l accumulation (off the critical path)
    float ls[16];
#pragma unroll
    for (int r = 0; r < 16; ++r) ls[r] = sv[0][r] + sv[1][r];
#pragma unroll
    for (int st = 8; st >= 1; st >>= 1)
#pragma unroll
      for (int r = 0; r < st; ++r) ls[r] += ls[r + st];
    l_run += ls[0] + __shfl_xor(ls[0], 32);
    if (t < 15) {  // transpose-write next V tile (conflict-free via XOR swizzle)
      ushort_t* Vw = smem + 16384 + (hh * 2 + (bb ^ 1)) * 4096;
#pragma unroll
      for (int e = 0; e < 8; ++e) {
        int f0 = (e ^ a2) << 3;
        Vw[(vdq + e) * 64 + (vj ^ f0)] = nv0[e];
        Vw[(vdq + 8 + e) * 64 + (vj ^ f0 ^ 8)] = nv1[e];
      }
      __syncthreads();  // drains gloads (vmcnt) + makes VT visible
    }
  }

  // ---- combine halves: pure sum of (O, l) through LDS (rotation addressing) ----
  __syncthreads();  // all K/V reads done; smem reusable
  float* exO = (float*)smem;                   // [4*64][32] fp32 = 32KB
  float* exl = (float*)(smem + 16384);         // [4*64] fp32 = 1KB (shorts offset 16384 = byte 32768)
  if (hh == 1) {
    float* eo = exO + (w4 * 64 + lane) * 32;
#pragma unroll
    for (int r = 0; r < 16; ++r) {
      eo[(r + lane) & 31] = oacc[0][r];
      eo[(16 + r + lane) & 31] = oacc[1][r];
    }
    exl[w4 * 64 + lane] = l_run;
  }
  __syncthreads();
  if (hh == 1) return;

  {
    const float* eo = exO + (w4 * 64 + lane) * 32;
#pragma unroll
    for (int r = 0; r < 16; ++r) {
      oacc[0][r] += eo[(r + lane) & 31];
      oacc[1][r] += eo[(16 + r + lane) & 31];
    }
    l_run += exl[w4 * 64 + lane];
  }

  // ---- memory retrieval + gated injection (waves 0-3 only) ----
  float den = 0.f;
  bf16x8 cqf[4];
  const float* nrm = mnorm + (size_t)(b * NHEAD + n) * 64;
#pragma unroll
  for (int ks = 0; ks < 4; ++ks) {
    u16x8 qv = *(const u16x8*)(qkv + qoff + ks * 16 + h * 8);
    union { u16x8 u; bf16x8 v; } cu;
#pragma unroll
    for (int e = 0; e < 8; ++e) {
      float x = bf2f(qv[e]);
      float c = (x > 0.f) ? (x + 1.f) : __builtin_amdgcn_exp2f(x * 1.4426950408889634f);
      cu.u[e] = f2bf(c);
      den += c * nrm[ks * 16 + h * 8 + e];
    }
    cqf[ks] = cu.v;
  }
  den += __shfl_xor(den, 32);

  const float* mb = mem + (size_t)(b * NHEAD + n) * 4096;
  f32x16 accv[2];
#pragma unroll
  for (int r = 0; r < 16; ++r) { accv[0][r] = 0.f; accv[1][r] = 0.f; }
#pragma unroll
  for (int db = 0; db < 2; ++db)
#pragma unroll
    for (int ks = 0; ks < 4; ++ks) {
      union { u16x8 u; bf16x8 v; } af;
#pragma unroll
      for (int e = 0; e < 8; ++e)
        af.u[e] = f2bf(mb[(size_t)(ks * 16 + h * 8 + e) * 64 + db * 32 + l31]);
      accv[db] = __builtin_amdgcn_mfma_f32_32x32x16_bf16(af.v, cqf[ks], accv[db], 0, 0, 0);
    }

  float g = 1.f / (1.f + expf(-gbeta[0]));
  float rden = 1.f / den, invl = 1.f / l_run;
  ushort_t* op = inj + (size_t)qrow * 2048 + b * 1024 + n * 64;
#pragma unroll
  for (int db = 0; db < 2; ++db)
#pragma unroll
    for (int qq = 0; qq < 4; ++qq) {
      u16x4 st;
#pragma unroll
      for (int m = 0; m < 4; ++m) {
        float content = accv[db][qq * 4 + m] * rden;
        float av = oacc[db][qq * 4 + m] * invl;
        st[m] = f2bf(g * content + (1.f - g) * av);
      }
      *(u16x4*)(op + db * 32 + qq * 8 + h * 4) = st;
    }
}

// ------------- y = h + attn_out; LayerNorm(D=1024) -------------
__global__ __launch_bounds__(256) void k_ln(const float* __restrict__ h,
                                            const float* __restrict__ ao,
                                            const float* __restrict__ gam,
                                            const float* __restrict__ bet,
                                            float* __restrict__ out) {
  const int m = blockIdx.x, t = threadIdx.x;
  const int lane = t & 63, w = t >> 6;
  __shared__ float redS[4], redQ[4];
  const size_t base = (size_t)m * 1024;
  float4 hv = ((const float4*)(h + base))[t];
  float4 avv = ((const float4*)(ao + base))[t];
  float y0 = hv.x + avv.x, y1 = hv.y + avv.y, y2 = hv.z + avv.z, y3 = hv.w + avv.w;
  float s = y0 + y1 + y2 + y3;
  float sq = y0 * y0 + y1 * y1 + y2 * y2 + y3 * y3;
#pragma unroll
  for (int mk = 32; mk >= 1; mk >>= 1) { s += __shfl_xor(s, mk); sq += __shfl_xor(sq, mk); }
  if (lane == 0) { redS[w] = s; redQ[w] = sq; }
  __syncthreads();
  float Ssum = redS[0] + redS[1] + redS[2] + redS[3];
  float Qsum = redQ[0] + redQ[1] + redQ[2] + redQ[3];
  float mu = Ssum * (1.f / 1024.f);
  float var = Qsum * (1.f / 1024.f) - mu * mu;
  float rstd = rsqrtf(var + 1e-5f);
  float4 g = ((const float4*)gam)[t];
  float4 bt = ((const float4*)bet)[t];
  float4 o;
  o.x = (y0 - mu) * rstd * g.x + bt.x;
  o.y = (y1 - mu) * rstd * g.y + bt.y;
  o.z = (y2 - mu) * rstd * g.z + bt.z;
  o.w = (y3 - mu) * rstd * g.w + bt.w;
  ((float4*)(out + base))[t] = o;
}

extern "C" void kernel_launch(void* const* d_in, const int* in_sizes, int n_in,
                              void* d_out, int out_size, void* d_ws, size_t ws_size,
                              hipStream_t stream) {
  const float* h = (const float*)d_in[0];
  const float* Wq = (const float*)d_in[1];
  const float* Wkv = (const float*)d_in[2];
  const float* Wo = (const float*)d_in[3];
  const float* gam = (const float*)d_in[4];
  const float* bet = (const float*)d_in[5];
  const float* mem = (const float*)d_in[6];
  const float* mnorm = (const float*)d_in[7];
  const float* gbeta = (const float*)d_in[8];
  float* out = (float*)d_out;

  char* ws = (char*)d_ws;
  // [0,8M) hb (reused as inj) | [8M,14M) wT | [14M,16M) woT | [16M,40M) qkv (reused as ao fp32)
  ushort_t* hb  = (ushort_t*)(ws);
  ushort_t* wT  = (ushort_t*)(ws + (size_t)(8u << 20));
  ushort_t* woT = (ushort_t*)(ws + (size_t)(14u << 20));
  ushort_t* qkv = (ushort_t*)(ws + (size_t)(16u << 20));
  float*    ao  = (float*)   (ws + (size_t)(16u << 20));  // alias qkv (dead by then)
  ushort_t* inj = hb;                                     // alias hb (dead by then)

  k_cvt_h<<<4096, 256, 0, stream>>>(h, hb, 1048576);
  k_cvt_wT<<<dim3(32, 32), 256, 0, stream>>>(Wq, wT, 1024, 1024);
  k_cvt_wT<<<dim3(64, 32), 256, 0, stream>>>(Wkv, wT + (size_t)1024 * 1024, 1024, 2048);
  k_cvt_wT<<<dim3(32, 32), 256, 0, stream>>>(Wo, woT, 1024, 1024);
  k_gemm_bt<1><<<768, 256, 0, stream>>>(hb, wT, (void*)qkv, 4096, 3072, 1024, 24);
  k_attn<<<dim3(16, 32), 512, 0, stream>>>(qkv, mem, mnorm, gbeta, inj);
  k_gemm64<<<512, 256, 0, stream>>>(inj, woT, ao, 4096, 1024, 1024, 8);
  k_ln<<<4096, 256, 0, stream>>>(h, ao, gam, bet, out);
}

// Round 6
// 146.986 us; speedup vs baseline: 1.1892x; 1.1892x over previous
//
#include <hip/hip_runtime.h>

// InfiniAttn forward on gfx950.
// cvt h->bf16 | transpose W->bf16 | GEMM qkv | V-transpose (global) | fused flash attn
// + mem-gate (256-thr, fixed-max softmax, prescaled Q, K & V^T both staged via
// global_load_lds with pre-swizzled source, double-buffered) | GEMM out 64x128 | +h,LN.

typedef unsigned short ushort_t;
typedef unsigned int uint32;

typedef __bf16 bf16x8 __attribute__((ext_vector_type(8)));
typedef float f32x4 __attribute__((ext_vector_type(4)));
typedef float f32x16 __attribute__((ext_vector_type(16)));
typedef unsigned short u16x8 __attribute__((ext_vector_type(8)));
typedef unsigned short u16x4 __attribute__((ext_vector_type(4)));
typedef unsigned int u32x4 __attribute__((ext_vector_type(4)));

typedef const __attribute__((address_space(1))) void gvoid_t;
typedef __attribute__((address_space(3))) void lvoid_t;

#define S_LEN 2048
#define BATCH 2
#define NHEAD 16

__device__ __forceinline__ ushort_t f2bf(float x) {
  union { float f; unsigned u; } c; c.f = x;
  unsigned r = (c.u + 0x7FFFu + ((c.u >> 16) & 1u)) >> 16;
  return (ushort_t)r;
}
__device__ __forceinline__ float bf2f(ushort_t v) {
  union { unsigned u; float f; } c; c.u = ((unsigned)v) << 16;
  return c.f;
}

// ---------------- dtype convert: h (fp32) -> bf16 ----------------
__global__ __launch_bounds__(256) void k_cvt_h(const float* __restrict__ src,
                                               ushort_t* __restrict__ dst, int n4) {
  int idx = blockIdx.x * 256 + threadIdx.x;
  if (idx >= n4) return;
  float4 v = ((const float4*)src)[idx];
  u16x4 o; o[0] = f2bf(v.x); o[1] = f2bf(v.y); o[2] = f2bf(v.z); o[3] = f2bf(v.w);
  ((u16x4*)dst)[idx] = o;
}

// ------------- transpose-convert: W[K][N] fp32 -> WT[N][K] bf16 -------------
__global__ __launch_bounds__(256) void k_cvt_wT(const float* __restrict__ W,
                                                ushort_t* __restrict__ WT, int K, int N) {
  __shared__ float tile[32][33];
  const int n0 = blockIdx.x * 32, k0 = blockIdx.y * 32;
  const int tx = threadIdx.x & 31, ty = threadIdx.x >> 5;
#pragma unroll
  for (int r = 0; r < 32; r += 8)
    tile[ty + r][tx] = W[(size_t)(k0 + ty + r) * N + n0 + tx];
  __syncthreads();
#pragma unroll
  for (int r = 0; r < 32; r += 8)
    WT[(size_t)(n0 + ty + r) * K + k0 + tx] = f2bf(tile[tx][ty + r]);
}

// ------------- GEMM 128x128: C = A[M][K](bf16) * B[N][K]^T(bf16), m97-style + XCD swizzle -------------
template <int OUT_BF16>
__global__ __launch_bounds__(256) void k_gemm_bt(const ushort_t* __restrict__ A,
                                                 const ushort_t* __restrict__ B,
                                                 void* __restrict__ Cv, int M, int N, int K,
                                                 int nbx) {
  __shared__ __attribute__((aligned(16))) ushort_t As[128 * 32];
  __shared__ __attribute__((aligned(16))) ushort_t Bs[128 * 32];
  const int per = gridDim.x >> 3;  // grid % 8 == 0
  const int fl = (blockIdx.x & 7) * per + (blockIdx.x >> 3);
  const int m0 = (fl / nbx) * 128, n0 = (fl % nbx) * 128;
  const int tid = threadIdx.x, w = tid >> 6, lane = tid & 63;
  const int wm = (w >> 1) * 64, wn = (w & 1) * 64;
  const int l15 = lane & 15, l4 = lane >> 4;
  f32x4 acc[4][4];
#pragma unroll
  for (int i = 0; i < 4; ++i)
#pragma unroll
    for (int j = 0; j < 4; ++j)
#pragma unroll
      for (int r = 0; r < 4; ++r) acc[i][j][r] = 0.f;

  for (int k0 = 0; k0 < K; k0 += 32) {
    __syncthreads();
#pragma unroll
    for (int r = 0; r < 2; ++r) {
      int c = r * 256 + w * 64 + lane;
      const ushort_t* ga = A + (size_t)(m0 + (c >> 2)) * K + k0 + (c & 3) * 8;
      const ushort_t* gb = B + (size_t)(n0 + (c >> 2)) * K + k0 + (c & 3) * 8;
      __builtin_amdgcn_global_load_lds((gvoid_t*)ga, (lvoid_t*)(As + (r * 256 + w * 64) * 8), 16, 0, 0);
      __builtin_amdgcn_global_load_lds((gvoid_t*)gb, (lvoid_t*)(Bs + (r * 256 + w * 64) * 8), 16, 0, 0);
    }
    __syncthreads();
    bf16x8 af[4], bfr[4];
#pragma unroll
    for (int i = 0; i < 4; ++i) af[i] = *(const bf16x8*)&As[(wm + i * 16 + l15) * 32 + l4 * 8];
#pragma unroll
    for (int j = 0; j < 4; ++j) bfr[j] = *(const bf16x8*)&Bs[(wn + j * 16 + l15) * 32 + l4 * 8];
#pragma unroll
    for (int i = 0; i < 4; ++i)
#pragma unroll
      for (int j = 0; j < 4; ++j)
        acc[i][j] = __builtin_amdgcn_mfma_f32_16x16x32_bf16(af[i], bfr[j], acc[i][j], 0, 0, 0);
  }
#pragma unroll
  for (int i = 0; i < 4; ++i)
#pragma unroll
    for (int j = 0; j < 4; ++j)
#pragma unroll
      for (int r = 0; r < 4; ++r) {
        int row = m0 + wm + i * 16 + l4 * 4 + r;
        int col = n0 + wn + j * 16 + l15;
        if (OUT_BF16)
          ((ushort_t*)Cv)[(size_t)row * N + col] = f2bf(acc[i][j][r]);
        else
          ((float*)Cv)[(size_t)row * N + col] = acc[i][j][r];
      }
}

// ------------- GEMM 64x128 tiles (for M=4096,N=1024: 512 blocks = 2/CU) -------------
__global__ __launch_bounds__(256) void k_gemm64(const ushort_t* __restrict__ A,
                                                const ushort_t* __restrict__ B,
                                                float* __restrict__ C, int M, int N, int K,
                                                int nbx) {
  __shared__ __attribute__((aligned(16))) ushort_t As[64 * 32];
  __shared__ __attribute__((aligned(16))) ushort_t Bs[128 * 32];
  const int per = gridDim.x >> 3;
  const int fl = (blockIdx.x & 7) * per + (blockIdx.x >> 3);
  const int m0 = (fl / nbx) * 64, n0 = (fl % nbx) * 128;
  const int tid = threadIdx.x, w = tid >> 6, lane = tid & 63;
  const int wn = w * 32;
  const int l15 = lane & 15, l4 = lane >> 4;
  f32x4 acc[4][2];
#pragma unroll
  for (int i = 0; i < 4; ++i)
#pragma unroll
    for (int j = 0; j < 2; ++j)
#pragma unroll
      for (int r = 0; r < 4; ++r) acc[i][j][r] = 0.f;

  for (int k0 = 0; k0 < K; k0 += 32) {
    __syncthreads();
    {
      int c = w * 64 + lane;
      const ushort_t* ga = A + (size_t)(m0 + (c >> 2)) * K + k0 + (c & 3) * 8;
      __builtin_amdgcn_global_load_lds((gvoid_t*)ga, (lvoid_t*)(As + w * 512), 16, 0, 0);
#pragma unroll
      for (int r = 0; r < 2; ++r) {
        int c2 = r * 256 + w * 64 + lane;
        const ushort_t* gb = B + (size_t)(n0 + (c2 >> 2)) * K + k0 + (c2 & 3) * 8;
        __builtin_amdgcn_global_load_lds((gvoid_t*)gb, (lvoid_t*)(Bs + r * 2048 + w * 512), 16, 0, 0);
      }
    }
    __syncthreads();
    bf16x8 af[4], bfr[2];
#pragma unroll
    for (int i = 0; i < 4; ++i) af[i] = *(const bf16x8*)&As[(i * 16 + l15) * 32 + l4 * 8];
#pragma unroll
    for (int j = 0; j < 2; ++j) bfr[j] = *(const bf16x8*)&Bs[(wn + j * 16 + l15) * 32 + l4 * 8];
#pragma unroll
    for (int i = 0; i < 4; ++i)
#pragma unroll
      for (int j = 0; j < 2; ++j)
        acc[i][j] = __builtin_amdgcn_mfma_f32_16x16x32_bf16(af[i], bfr[j], acc[i][j], 0, 0, 0);
  }
#pragma unroll
  for (int i = 0; i < 4; ++i)
#pragma unroll
    for (int j = 0; j < 2; ++j)
#pragma unroll
      for (int r = 0; r < 4; ++r)
        C[(size_t)(m0 + i * 16 + l4 * 4 + r) * N + n0 + wn + j * 16 + l15] = acc[i][j][r];
}

// ------------- V transpose: qkv V-part -> VT[bn][d][j] (bf16), once per (b,n) -------------
__global__ __launch_bounds__(256) void k_vt(const ushort_t* __restrict__ qkv,
                                            ushort_t* __restrict__ vt) {
  __shared__ uint32 tile[64 * 65];
  const int jt = blockIdx.x, bn = blockIdx.y, b = bn & 1, n = bn >> 1;
  const int tid = threadIdx.x;
  const int j0 = jt * 64;
#pragma unroll
  for (int rr = 0; rr < 2; ++rr) {
    int lin = rr * 2048 + tid * 8;
    int j = lin >> 6, d0 = lin & 63;
    u16x8 v = *(const u16x8*)(qkv + (size_t)(j0 + j) * 6144 + b * 3072 + 2048 + n * 64 + d0);
#pragma unroll
    for (int e = 0; e < 8; ++e) tile[j * 65 + d0 + e] = v[e];
  }
  __syncthreads();
#pragma unroll
  for (int rr = 0; rr < 2; ++rr) {
    int lin = rr * 2048 + tid * 8;
    int d = lin >> 6, jj = lin & 63;
    u16x8 o;
#pragma unroll
    for (int e = 0; e < 8; ++e) o[e] = (ushort_t)tile[(jj + e) * 65 + d];
    *(u16x8*)(vt + ((size_t)bn * 64 + d) * 2048 + j0 + jj) = o;
  }
}

// ------------- staging: global_load_lds with pre-swizzled source -------------
// LDS layout [64 rows][8 slots x 8 shorts]; LDS[row][s] = src[row][s ^ (row&7)].
__device__ __forceinline__ void stage_k(const ushort_t* __restrict__ qkv, ushort_t* kw,
                                        int j0, int b, int n, int w, int lane) {
#pragma unroll
  for (int r = 0; r < 2; ++r) {
    int jb_ = w * 16 + r * 8;  // multiple of 8 -> (row&7) == lane>>3
    const ushort_t* ksrc = qkv + (size_t)(j0 + jb_ + (lane >> 3)) * 6144 + b * 3072 + n * 64 + 1024
                           + (((lane & 7) ^ (lane >> 3)) << 3);
    __builtin_amdgcn_global_load_lds((gvoid_t*)ksrc, (lvoid_t*)(kw + jb_ * 64), 16, 0, 0);
  }
}
__device__ __forceinline__ void stage_vt(const ushort_t* __restrict__ vt, ushort_t* vw,
                                         int j0, int bn, int w, int lane) {
#pragma unroll
  for (int r = 0; r < 2; ++r) {
    int db_ = w * 16 + r * 8;  // d-rows
    const ushort_t* vsrc = vt + ((size_t)bn * 64 + db_ + (lane >> 3)) * 2048 + j0
                           + (((lane & 7) ^ (lane >> 3)) << 3);
    __builtin_amdgcn_global_load_lds((gvoid_t*)vsrc, (lvoid_t*)(vw + db_ * 64), 16, 0, 0);
  }
}

// ------------- fused flash attention + memory gate (256 thr, fixed-max) -------------
// Fixed-max softmax: scores analytically bounded; P = exp(s), l = sum P.
// Q prescaled by 0.125*log2(e) so exp2(sv) = e^s.
__global__ __launch_bounds__(256) void k_attn(const ushort_t* __restrict__ qkv,
                                              const ushort_t* __restrict__ vt,
                                              const float* __restrict__ mem,
                                              const float* __restrict__ mnorm,
                                              const float* __restrict__ gbeta,
                                              ushort_t* __restrict__ inj) {
  __shared__ __attribute__((aligned(16))) ushort_t Ks[2][4096];
  __shared__ __attribute__((aligned(16))) ushort_t VTs[2][4096];
  const int bn = blockIdx.y, b = bn & 1, n = bn >> 1;
  const int tid = threadIdx.x, w = tid >> 6, lane = tid & 63;
  const int l31 = lane & 31, h = lane >> 5;
  const int qrow = blockIdx.x * 128 + w * 32 + l31;
  const size_t qoff = (size_t)qrow * 6144 + b * 3072 + n * 64;
  const float CEXP = 0.18033688011113723f;  // 0.125 * log2(e)
  // prescaled Q fragments
  bf16x8 qf[4];
#pragma unroll
  for (int ks = 0; ks < 4; ++ks) {
    u16x8 qv = *(const u16x8*)(qkv + qoff + ks * 16 + h * 8);
    union { u16x8 u; bf16x8 v; } cu;
#pragma unroll
    for (int e = 0; e < 8; ++e) cu.u[e] = f2bf(bf2f(qv[e]) * CEXP);
    qf[ks] = cu.v;
  }
  const int krd = l31 & 7;

  // ---- prologue: stage tile 0 ----
  stage_k(qkv, Ks[0], 0, b, n, w, lane);
  stage_vt(vt, VTs[0], 0, bn, w, lane);
  __syncthreads();

  f32x16 oacc[2];
#pragma unroll
  for (int r = 0; r < 16; ++r) { oacc[0][r] = 0.f; oacc[1][r] = 0.f; }
  float l_run = 0.f;

  for (int t = 0; t < 32; ++t) {
    const ushort_t* Kb = Ks[t & 1];
    const ushort_t* Vb = VTs[t & 1];
    if (t < 31) {  // async prefetch of tile t+1 (both via global_load_lds)
      stage_k(qkv, Ks[(t + 1) & 1], (t + 1) * 64, b, n, w, lane);
      stage_vt(vt, VTs[(t + 1) & 1], (t + 1) * 64, bn, w, lane);
    }
    // S^T = mfma(A=K, B=Q): lane holds S[own q=l31][j = jb*32 + (r&3)+8*(r>>2)+4h]
    f32x16 sv[2];
#pragma unroll
    for (int r = 0; r < 16; ++r) { sv[0][r] = 0.f; sv[1][r] = 0.f; }
    __builtin_amdgcn_s_setprio(1);
#pragma unroll
    for (int jb = 0; jb < 2; ++jb) {
      const int rb = (jb * 32 + l31) * 64;
#pragma unroll
      for (int ks = 0; ks < 4; ++ks) {
        bf16x8 kf = *(const bf16x8*)&Kb[rb + ((((ks << 1) | h) ^ krd) << 3)];
        sv[jb] = __builtin_amdgcn_mfma_f32_32x32x16_bf16(kf, qf[ks], sv[jb], 0, 0, 0);
      }
    }
    __builtin_amdgcn_s_setprio(0);
    // fixed-max softmax: p = exp2(sv) in place
#pragma unroll
    for (int jb = 0; jb < 2; ++jb)
#pragma unroll
      for (int r = 0; r < 16; ++r)
        sv[jb][r] = __builtin_amdgcn_exp2f(sv[jb][r]);
    // PV: O^T = mfma(A=V^T, B=P^T); P-frags via cvt_pk + permlane32_swap (T12)
#pragma unroll
    for (int ks = 0; ks < 4; ++ks) {
      const int jb = ks >> 1, q0 = (ks & 1) * 2;
      uint32 X0, X1, Y0, Y1;
      asm volatile("v_cvt_pk_bf16_f32 %0, %1, %2" : "=v"(X0) : "v"(sv[jb][q0 * 4 + 0]), "v"(sv[jb][q0 * 4 + 1]));
      asm volatile("v_cvt_pk_bf16_f32 %0, %1, %2" : "=v"(X1) : "v"(sv[jb][q0 * 4 + 2]), "v"(sv[jb][q0 * 4 + 3]));
      asm volatile("v_cvt_pk_bf16_f32 %0, %1, %2" : "=v"(Y0) : "v"(sv[jb][(q0 + 1) * 4 + 0]), "v"(sv[jb][(q0 + 1) * 4 + 1]));
      asm volatile("v_cvt_pk_bf16_f32 %0, %1, %2" : "=v"(Y1) : "v"(sv[jb][(q0 + 1) * 4 + 2]), "v"(sv[jb][(q0 + 1) * 4 + 3]));
      asm volatile("v_permlane32_swap_b32 %0, %1" : "+v"(X0), "+v"(Y0));
      asm volatile("v_permlane32_swap_b32 %0, %1" : "+v"(X1), "+v"(Y1));
      union { u32x4 u; bf16x8 v; } pf;
      pf.u[0] = X0; pf.u[1] = X1; pf.u[2] = Y0; pf.u[3] = Y1;
      const int g = ((((ks << 1) | h) ^ krd) << 3);
      bf16x8 vf0 = *(const bf16x8*)&Vb[l31 * 64 + g];
      bf16x8 vf1 = *(const bf16x8*)&Vb[(32 + l31) * 64 + g];
      __builtin_amdgcn_s_setprio(1);
      oacc[0] = __builtin_amdgcn_mfma_f32_32x32x16_bf16(vf0, pf.v, oacc[0], 0, 0, 0);
      oacc[1] = __builtin_amdgcn_mfma_f32_32x32x16_bf16(vf1, pf.v, oacc[1], 0, 0, 0);
      __builtin_amdgcn_s_setprio(0);
    }
    // l accumulation (off the critical path)
    float ls[16];
#pragma unroll
    for (int r = 0; r < 16; ++r) ls[r] = sv[0][r] + sv[1][r];
#pragma unroll
    for (int st = 8; st >= 1; st >>= 1)
#pragma unroll
      for (int r = 0; r < st; ++r) ls[r] += ls[r + st];
    l_run += ls[0] + __shfl_xor(ls[0], 32);
    if (t < 31) __syncthreads();  // drains gloads (vmcnt) + buffer handoff
  }

  // ---- epilogue: memory retrieval + gated injection (fused gate) ----
  float den = 0.f;
  bf16x8 cqf[4];
  const float* nrm = mnorm + (size_t)(b * NHEAD + n) * 64;
#pragma unroll
  for (int ks = 0; ks < 4; ++ks) {
    u16x8 qv = *(const u16x8*)(qkv + qoff + ks * 16 + h * 8);
    union { u16x8 u; bf16x8 v; } cu;
#pragma unroll
    for (int e = 0; e < 8; ++e) {
      float x = bf2f(qv[e]);
      float c = (x > 0.f) ? (x + 1.f) : __builtin_amdgcn_exp2f(x * 1.4426950408889634f);
      cu.u[e] = f2bf(c);
      den += c * nrm[ks * 16 + h * 8 + e];
    }
    cqf[ks] = cu.v;
  }
  den += __shfl_xor(den, 32);

  const float* mb = mem + (size_t)(b * NHEAD + n) * 4096;
  f32x16 accv[2];
#pragma unroll
  for (int r = 0; r < 16; ++r) { accv[0][r] = 0.f; accv[1][r] = 0.f; }
#pragma unroll
  for (int db = 0; db < 2; ++db)
#pragma unroll
    for (int ks = 0; ks < 4; ++ks) {
      union { u16x8 u; bf16x8 v; } af;
#pragma unroll
      for (int e = 0; e < 8; ++e)
        af.u[e] = f2bf(mb[(size_t)(ks * 16 + h * 8 + e) * 64 + db * 32 + l31]);
      accv[db] = __builtin_amdgcn_mfma_f32_32x32x16_bf16(af.v, cqf[ks], accv[db], 0, 0, 0);
    }

  float g = 1.f / (1.f + expf(-gbeta[0]));
  float rden = 1.f / den, invl = 1.f / l_run;
  ushort_t* op = inj + (size_t)qrow * 2048 + b * 1024 + n * 64;
#pragma unroll
  for (int db = 0; db < 2; ++db)
#pragma unroll
    for (int qq = 0; qq < 4; ++qq) {
      u16x4 st;
#pragma unroll
      for (int m = 0; m < 4; ++m) {
        float content = accv[db][qq * 4 + m] * rden;
        float av = oacc[db][qq * 4 + m] * invl;
        st[m] = f2bf(g * content + (1.f - g) * av);
      }
      *(u16x4*)(op + db * 32 + qq * 8 + h * 4) = st;
    }
}

// ------------- y = h + attn_out; LayerNorm(D=1024) -------------
__global__ __launch_bounds__(256) void k_ln(const float* __restrict__ h,
                                            const float* __restrict__ ao,
                                            const float* __restrict__ gam,
                                            const float* __restrict__ bet,
                                            float* __restrict__ out) {
  const int m = blockIdx.x, t = threadIdx.x;
  const int lane = t & 63, w = t >> 6;
  __shared__ float redS[4], redQ[4];
  const size_t base = (size_t)m * 1024;
  float4 hv = ((const float4*)(h + base))[t];
  float4 avv = ((const float4*)(ao + base))[t];
  float y0 = hv.x + avv.x, y1 = hv.y + avv.y, y2 = hv.z + avv.z, y3 = hv.w + avv.w;
  float s = y0 + y1 + y2 + y3;
  float sq = y0 * y0 + y1 * y1 + y2 * y2 + y3 * y3;
#pragma unroll
  for (int mk = 32; mk >= 1; mk >>= 1) { s += __shfl_xor(s, mk); sq += __shfl_xor(sq, mk); }
  if (lane == 0) { redS[w] = s; redQ[w] = sq; }
  __syncthreads();
  float Ssum = redS[0] + redS[1] + redS[2] + redS[3];
  float Qsum = redQ[0] + redQ[1] + redQ[2] + redQ[3];
  float mu = Ssum * (1.f / 1024.f);
  float var = Qsum * (1.f / 1024.f) - mu * mu;
  float rstd = rsqrtf(var + 1e-5f);
  float4 g = ((const float4*)gam)[t];
  float4 bt = ((const float4*)bet)[t];
  float4 o;
  o.x = (y0 - mu) * rstd * g.x + bt.x;
  o.y = (y1 - mu) * rstd * g.y + bt.y;
  o.z = (y2 - mu) * rstd * g.z + bt.z;
  o.w = (y3 - mu) * rstd * g.w + bt.w;
  ((float4*)(out + base))[t] = o;
}

extern "C" void kernel_launch(void* const* d_in, const int* in_sizes, int n_in,
                              void* d_out, int out_size, void* d_ws, size_t ws_size,
                              hipStream_t stream) {
  const float* h = (const float*)d_in[0];
  const float* Wq = (const float*)d_in[1];
  const float* Wkv = (const float*)d_in[2];
  const float* Wo = (const float*)d_in[3];
  const float* gam = (const float*)d_in[4];
  const float* bet = (const float*)d_in[5];
  const float* mem = (const float*)d_in[6];
  const float* mnorm = (const float*)d_in[7];
  const float* gbeta = (const float*)d_in[8];
  float* out = (float*)d_out;

  char* ws = (char*)d_ws;
  // [0,8M) hb (reused as inj) | [8M,14M) wT | [14M,16M) woT |
  // [16M,40M) qkv (reused as ao fp32) | [40M,48M) vt
  ushort_t* hb  = (ushort_t*)(ws);
  ushort_t* wT  = (ushort_t*)(ws + (size_t)(8u << 20));
  ushort_t* woT = (ushort_t*)(ws + (size_t)(14u << 20));
  ushort_t* qkv = (ushort_t*)(ws + (size_t)(16u << 20));
  float*    ao  = (float*)   (ws + (size_t)(16u << 20));  // alias qkv (dead by then)
  ushort_t* vtb = (ushort_t*)(ws + (size_t)(40u << 20));
  ushort_t* inj = hb;                                     // alias hb (dead by then)

  k_cvt_h<<<4096, 256, 0, stream>>>(h, hb, 1048576);
  k_cvt_wT<<<dim3(32, 32), 256, 0, stream>>>(Wq, wT, 1024, 1024);
  k_cvt_wT<<<dim3(64, 32), 256, 0, stream>>>(Wkv, wT + (size_t)1024 * 1024, 1024, 2048);
  k_cvt_wT<<<dim3(32, 32), 256, 0, stream>>>(Wo, woT, 1024, 1024);
  k_gemm_bt<1><<<768, 256, 0, stream>>>(hb, wT, (void*)qkv, 4096, 3072, 1024, 24);
  k_vt<<<dim3(32, 32), 256, 0, stream>>>(qkv, vtb);
  k_attn<<<dim3(16, 32), 256, 0, stream>>>(qkv, vtb, mem, mnorm, gbeta, inj);
  k_gemm64<<<512, 256, 0, stream>>>(inj, woT, ao, 4096, 1024, 1024, 8);
  k_ln<<<4096, 256, 0, stream>>>(h, ao, gam, bet, out);
}

// Round 7
// 145.811 us; speedup vs baseline: 1.1988x; 1.0081x over previous
//
#include <hip/hip_runtime.h>

// InfiniAttn forward on gfx950.
// cvt h->bf16 | transpose W->bf16 | GEMM qkv | V-transpose (global) | fused flash attn
// + mem-gate (256-thr, fixed-max softmax, prescaled Q, K & V^T staged via global_load_lds
// with pre-swizzled source g(r)=(r&7)^(r>>3), l via ones-MFMA) | GEMM out 64x128 | +h,LN.

typedef unsigned short ushort_t;
typedef unsigned int uint32;

typedef __bf16 bf16x8 __attribute__((ext_vector_type(8)));
typedef float f32x4 __attribute__((ext_vector_type(4)));
typedef float f32x16 __attribute__((ext_vector_type(16)));
typedef unsigned short u16x8 __attribute__((ext_vector_type(8)));
typedef unsigned short u16x4 __attribute__((ext_vector_type(4)));
typedef unsigned int u32x4 __attribute__((ext_vector_type(4)));

typedef const __attribute__((address_space(1))) void gvoid_t;
typedef __attribute__((address_space(3))) void lvoid_t;

#define S_LEN 2048
#define BATCH 2
#define NHEAD 16

__device__ __forceinline__ ushort_t f2bf(float x) {
  union { float f; unsigned u; } c; c.f = x;
  unsigned r = (c.u + 0x7FFFu + ((c.u >> 16) & 1u)) >> 16;
  return (ushort_t)r;
}
__device__ __forceinline__ float bf2f(ushort_t v) {
  union { unsigned u; float f; } c; c.u = ((unsigned)v) << 16;
  return c.f;
}

// ---------------- dtype convert: h (fp32) -> bf16 ----------------
__global__ __launch_bounds__(256) void k_cvt_h(const float* __restrict__ src,
                                               ushort_t* __restrict__ dst, int n4) {
  int idx = blockIdx.x * 256 + threadIdx.x;
  if (idx >= n4) return;
  float4 v = ((const float4*)src)[idx];
  u16x4 o; o[0] = f2bf(v.x); o[1] = f2bf(v.y); o[2] = f2bf(v.z); o[3] = f2bf(v.w);
  ((u16x4*)dst)[idx] = o;
}

// ------------- transpose-convert: W[K][N] fp32 -> WT[N][K] bf16 -------------
__global__ __launch_bounds__(256) void k_cvt_wT(const float* __restrict__ W,
                                                ushort_t* __restrict__ WT, int K, int N) {
  __shared__ float tile[32][33];
  const int n0 = blockIdx.x * 32, k0 = blockIdx.y * 32;
  const int tx = threadIdx.x & 31, ty = threadIdx.x >> 5;
#pragma unroll
  for (int r = 0; r < 32; r += 8)
    tile[ty + r][tx] = W[(size_t)(k0 + ty + r) * N + n0 + tx];
  __syncthreads();
#pragma unroll
  for (int r = 0; r < 32; r += 8)
    WT[(size_t)(n0 + ty + r) * K + k0 + tx] = f2bf(tile[tx][ty + r]);
}

// ------------- GEMM 128x128: C = A[M][K](bf16) * B[N][K]^T(bf16), m97-style + XCD swizzle -------------
template <int OUT_BF16>
__global__ __launch_bounds__(256) void k_gemm_bt(const ushort_t* __restrict__ A,
                                                 const ushort_t* __restrict__ B,
                                                 void* __restrict__ Cv, int M, int N, int K,
                                                 int nbx) {
  __shared__ __attribute__((aligned(16))) ushort_t As[128 * 32];
  __shared__ __attribute__((aligned(16))) ushort_t Bs[128 * 32];
  const int per = gridDim.x >> 3;  // grid % 8 == 0
  const int fl = (blockIdx.x & 7) * per + (blockIdx.x >> 3);
  const int m0 = (fl / nbx) * 128, n0 = (fl % nbx) * 128;
  const int tid = threadIdx.x, w = tid >> 6, lane = tid & 63;
  const int wm = (w >> 1) * 64, wn = (w & 1) * 64;
  const int l15 = lane & 15, l4 = lane >> 4;
  f32x4 acc[4][4];
#pragma unroll
  for (int i = 0; i < 4; ++i)
#pragma unroll
    for (int j = 0; j < 4; ++j)
#pragma unroll
      for (int r = 0; r < 4; ++r) acc[i][j][r] = 0.f;

  for (int k0 = 0; k0 < K; k0 += 32) {
    __syncthreads();
#pragma unroll
    for (int r = 0; r < 2; ++r) {
      int c = r * 256 + w * 64 + lane;
      const ushort_t* ga = A + (size_t)(m0 + (c >> 2)) * K + k0 + (c & 3) * 8;
      const ushort_t* gb = B + (size_t)(n0 + (c >> 2)) * K + k0 + (c & 3) * 8;
      __builtin_amdgcn_global_load_lds((gvoid_t*)ga, (lvoid_t*)(As + (r * 256 + w * 64) * 8), 16, 0, 0);
      __builtin_amdgcn_global_load_lds((gvoid_t*)gb, (lvoid_t*)(Bs + (r * 256 + w * 64) * 8), 16, 0, 0);
    }
    __syncthreads();
    bf16x8 af[4], bfr[4];
#pragma unroll
    for (int i = 0; i < 4; ++i) af[i] = *(const bf16x8*)&As[(wm + i * 16 + l15) * 32 + l4 * 8];
#pragma unroll
    for (int j = 0; j < 4; ++j) bfr[j] = *(const bf16x8*)&Bs[(wn + j * 16 + l15) * 32 + l4 * 8];
#pragma unroll
    for (int i = 0; i < 4; ++i)
#pragma unroll
      for (int j = 0; j < 4; ++j)
        acc[i][j] = __builtin_amdgcn_mfma_f32_16x16x32_bf16(af[i], bfr[j], acc[i][j], 0, 0, 0);
  }
#pragma unroll
  for (int i = 0; i < 4; ++i)
#pragma unroll
    for (int j = 0; j < 4; ++j)
#pragma unroll
      for (int r = 0; r < 4; ++r) {
        int row = m0 + wm + i * 16 + l4 * 4 + r;
        int col = n0 + wn + j * 16 + l15;
        if (OUT_BF16)
          ((ushort_t*)Cv)[(size_t)row * N + col] = f2bf(acc[i][j][r]);
        else
          ((float*)Cv)[(size_t)row * N + col] = acc[i][j][r];
      }
}

// ------------- GEMM 64x128 tiles (for M=4096,N=1024: 512 blocks = 2/CU) -------------
__global__ __launch_bounds__(256) void k_gemm64(const ushort_t* __restrict__ A,
                                                const ushort_t* __restrict__ B,
                                                float* __restrict__ C, int M, int N, int K,
                                                int nbx) {
  __shared__ __attribute__((aligned(16))) ushort_t As[64 * 32];
  __shared__ __attribute__((aligned(16))) ushort_t Bs[128 * 32];
  const int per = gridDim.x >> 3;
  const int fl = (blockIdx.x & 7) * per + (blockIdx.x >> 3);
  const int m0 = (fl / nbx) * 64, n0 = (fl % nbx) * 128;
  const int tid = threadIdx.x, w = tid >> 6, lane = tid & 63;
  const int wn = w * 32;
  const int l15 = lane & 15, l4 = lane >> 4;
  f32x4 acc[4][2];
#pragma unroll
  for (int i = 0; i < 4; ++i)
#pragma unroll
    for (int j = 0; j < 2; ++j)
#pragma unroll
      for (int r = 0; r < 4; ++r) acc[i][j][r] = 0.f;

  for (int k0 = 0; k0 < K; k0 += 32) {
    __syncthreads();
    {
      int c = w * 64 + lane;
      const ushort_t* ga = A + (size_t)(m0 + (c >> 2)) * K + k0 + (c & 3) * 8;
      __builtin_amdgcn_global_load_lds((gvoid_t*)ga, (lvoid_t*)(As + w * 512), 16, 0, 0);
#pragma unroll
      for (int r = 0; r < 2; ++r) {
        int c2 = r * 256 + w * 64 + lane;
        const ushort_t* gb = B + (size_t)(n0 + (c2 >> 2)) * K + k0 + (c2 & 3) * 8;
        __builtin_amdgcn_global_load_lds((gvoid_t*)gb, (lvoid_t*)(Bs + r * 2048 + w * 512), 16, 0, 0);
      }
    }
    __syncthreads();
    bf16x8 af[4], bfr[2];
#pragma unroll
    for (int i = 0; i < 4; ++i) af[i] = *(const bf16x8*)&As[(i * 16 + l15) * 32 + l4 * 8];
#pragma unroll
    for (int j = 0; j < 2; ++j) bfr[j] = *(const bf16x8*)&Bs[(wn + j * 16 + l15) * 32 + l4 * 8];
#pragma unroll
    for (int i = 0; i < 4; ++i)
#pragma unroll
      for (int j = 0; j < 2; ++j)
        acc[i][j] = __builtin_amdgcn_mfma_f32_16x16x32_bf16(af[i], bfr[j], acc[i][j], 0, 0, 0);
  }
#pragma unroll
  for (int i = 0; i < 4; ++i)
#pragma unroll
    for (int j = 0; j < 2; ++j)
#pragma unroll
      for (int r = 0; r < 4; ++r)
        C[(size_t)(m0 + i * 16 + l4 * 4 + r) * N + n0 + wn + j * 16 + l15] = acc[i][j][r];
}

// ------------- V transpose: qkv V-part -> VT[bn][d][j] (bf16), once per (b,n) -------------
__global__ __launch_bounds__(256) void k_vt(const ushort_t* __restrict__ qkv,
                                            ushort_t* __restrict__ vt) {
  __shared__ uint32 tile[64 * 65];
  const int jt = blockIdx.x, bn = blockIdx.y, b = bn & 1, n = bn >> 1;
  const int tid = threadIdx.x;
  const int j0 = jt * 64;
#pragma unroll
  for (int rr = 0; rr < 2; ++rr) {
    int lin = rr * 2048 + tid * 8;
    int j = lin >> 6, d0 = lin & 63;
    u16x8 v = *(const u16x8*)(qkv + (size_t)(j0 + j) * 6144 + b * 3072 + 2048 + n * 64 + d0);
#pragma unroll
    for (int e = 0; e < 8; ++e) tile[j * 65 + d0 + e] = v[e];
  }
  __syncthreads();
#pragma unroll
  for (int rr = 0; rr < 2; ++rr) {
    int lin = rr * 2048 + tid * 8;
    int d = lin >> 6, jj = lin & 63;
    u16x8 o;
#pragma unroll
    for (int e = 0; e < 8; ++e) o[e] = (ushort_t)tile[(jj + e) * 65 + d];
    *(u16x8*)(vt + ((size_t)bn * 64 + d) * 2048 + j0 + jj) = o;
  }
}

// ------------- staging: global_load_lds with pre-swizzled source -------------
// LDS layout [64 rows][8 slots x 8 shorts]; LDS[row][s] = src[row][s ^ g(row)],
// g(row) = (row&7) ^ ((row>>3)&7).  Per call rows jb_..jb_+7: (row>>3) = jb8 const.
__device__ __forceinline__ void stage_k(const ushort_t* __restrict__ qkv, ushort_t* kw,
                                        int j0, int b, int n, int w, int lane) {
#pragma unroll
  for (int r = 0; r < 2; ++r) {
    int jb_ = w * 16 + r * 8;
    int jb8 = w * 2 + r;
    const ushort_t* ksrc = qkv + (size_t)(j0 + jb_ + (lane >> 3)) * 6144 + b * 3072 + n * 64 + 1024
                           + ((((lane & 7) ^ (lane >> 3) ^ jb8) & 7) << 3);
    __builtin_amdgcn_global_load_lds((gvoid_t*)ksrc, (lvoid_t*)(kw + jb_ * 64), 16, 0, 0);
  }
}
__device__ __forceinline__ void stage_vt(const ushort_t* __restrict__ vt, ushort_t* vw,
                                         int j0, int bn, int w, int lane) {
#pragma unroll
  for (int r = 0; r < 2; ++r) {
    int db_ = w * 16 + r * 8;
    int jb8 = w * 2 + r;
    const ushort_t* vsrc = vt + ((size_t)bn * 64 + db_ + (lane >> 3)) * 2048 + j0
                           + ((((lane & 7) ^ (lane >> 3) ^ jb8) & 7) << 3);
    __builtin_amdgcn_global_load_lds((gvoid_t*)vsrc, (lvoid_t*)(vw + db_ * 64), 16, 0, 0);
  }
}

// ------------- fused flash attention + memory gate (256 thr, fixed-max) -------------
// Fixed-max softmax: scores analytically bounded; P = exp(s), l = sum P via ones-MFMA.
// Q prescaled by 0.125*log2(e) so exp2(sv) = e^s.
__global__ __launch_bounds__(256) void k_attn(const ushort_t* __restrict__ qkv,
                                              const ushort_t* __restrict__ vt,
                                              const float* __restrict__ mem,
                                              const float* __restrict__ mnorm,
                                              const float* __restrict__ gbeta,
                                              ushort_t* __restrict__ inj) {
  __shared__ __attribute__((aligned(16))) ushort_t Ks[2][4096];
  __shared__ __attribute__((aligned(16))) ushort_t VTs[2][4096];
  const int bn = blockIdx.y, b = bn & 1, n = bn >> 1;
  const int tid = threadIdx.x, w = tid >> 6, lane = tid & 63;
  const int l31 = lane & 31, h = lane >> 5;
  const int qrow = blockIdx.x * 128 + w * 32 + l31;
  const size_t qoff = (size_t)qrow * 6144 + b * 3072 + n * 64;
  const float CEXP = 0.18033688011113723f;  // 0.125 * log2(e)
  // prescaled Q fragments
  bf16x8 qf[4];
#pragma unroll
  for (int ks = 0; ks < 4; ++ks) {
    u16x8 qv = *(const u16x8*)(qkv + qoff + ks * 16 + h * 8);
    union { u16x8 u; bf16x8 v; } cu;
#pragma unroll
    for (int e = 0; e < 8; ++e) cu.u[e] = f2bf(bf2f(qv[e]) * CEXP);
    qf[ks] = cu.v;
  }
  const int fA = (l31 & 7) ^ (l31 >> 3);  // read swizzle rows 0-31; rows 32-63: fA^4
  const int fB = fA ^ 4;
  union { u16x8 u; bf16x8 v; } ones;
#pragma unroll
  for (int e = 0; e < 8; ++e) ones.u[e] = 0x3F80;  // bf16 1.0

  // ---- prologue: stage tile 0 ----
  stage_k(qkv, Ks[0], 0, b, n, w, lane);
  stage_vt(vt, VTs[0], 0, bn, w, lane);
  __syncthreads();

  f32x16 oacc[2], lacc;
#pragma unroll
  for (int r = 0; r < 16; ++r) { oacc[0][r] = 0.f; oacc[1][r] = 0.f; lacc[r] = 0.f; }

  for (int t = 0; t < 32; ++t) {
    const ushort_t* Kb = Ks[t & 1];
    const ushort_t* Vb = VTs[t & 1];
    if (t < 31) {  // async prefetch of tile t+1 (both via global_load_lds)
      stage_k(qkv, Ks[(t + 1) & 1], (t + 1) * 64, b, n, w, lane);
      stage_vt(vt, VTs[(t + 1) & 1], (t + 1) * 64, bn, w, lane);
    }
    // S^T = mfma(A=K, B=Q): lane holds S[own q=l31][j = jb*32 + (r&3)+8*(r>>2)+4h]
    f32x16 sv[2];
#pragma unroll
    for (int r = 0; r < 16; ++r) { sv[0][r] = 0.f; sv[1][r] = 0.f; }
    __builtin_amdgcn_s_setprio(1);
#pragma unroll
    for (int jb = 0; jb < 2; ++jb) {
      const int rb = (jb * 32 + l31) * 64;
      const int fj = jb ? fB : fA;
#pragma unroll
      for (int ks = 0; ks < 4; ++ks) {
        bf16x8 kf = *(const bf16x8*)&Kb[rb + ((((ks << 1) | h) ^ fj) << 3)];
        sv[jb] = __builtin_amdgcn_mfma_f32_32x32x16_bf16(kf, qf[ks], sv[jb], 0, 0, 0);
      }
    }
    __builtin_amdgcn_s_setprio(0);
    // fixed-max softmax: p = exp2(sv) in place
#pragma unroll
    for (int jb = 0; jb < 2; ++jb)
#pragma unroll
      for (int r = 0; r < 16; ++r)
        sv[jb][r] = __builtin_amdgcn_exp2f(sv[jb][r]);
    // PV: O^T = mfma(A=V^T, B=P^T); P-frags via cvt_pk + permlane32_swap (T12).
    // l = sum_j P via ones-MFMA (replaces VALU tree; exactly matches bf16 P).
#pragma unroll
    for (int ks = 0; ks < 4; ++ks) {
      const int jb = ks >> 1, q0 = (ks & 1) * 2;
      uint32 X0, X1, Y0, Y1;
      asm volatile("v_cvt_pk_bf16_f32 %0, %1, %2" : "=v"(X0) : "v"(sv[jb][q0 * 4 + 0]), "v"(sv[jb][q0 * 4 + 1]));
      asm volatile("v_cvt_pk_bf16_f32 %0, %1, %2" : "=v"(X1) : "v"(sv[jb][q0 * 4 + 2]), "v"(sv[jb][q0 * 4 + 3]));
      asm volatile("v_cvt_pk_bf16_f32 %0, %1, %2" : "=v"(Y0) : "v"(sv[jb][(q0 + 1) * 4 + 0]), "v"(sv[jb][(q0 + 1) * 4 + 1]));
      asm volatile("v_cvt_pk_bf16_f32 %0, %1, %2" : "=v"(Y1) : "v"(sv[jb][(q0 + 1) * 4 + 2]), "v"(sv[jb][(q0 + 1) * 4 + 3]));
      asm volatile("v_permlane32_swap_b32 %0, %1" : "+v"(X0), "+v"(Y0));
      asm volatile("v_permlane32_swap_b32 %0, %1" : "+v"(X1), "+v"(Y1));
      union { u32x4 u; bf16x8 v; } pf;
      pf.u[0] = X0; pf.u[1] = X1; pf.u[2] = Y0; pf.u[3] = Y1;
      const int c = (ks << 1) | h;
      bf16x8 vf0 = *(const bf16x8*)&Vb[l31 * 64 + ((c ^ fA) << 3)];
      bf16x8 vf1 = *(const bf16x8*)&Vb[(32 + l31) * 64 + ((c ^ fB) << 3)];
      __builtin_amdgcn_s_setprio(1);
      oacc[0] = __builtin_amdgcn_mfma_f32_32x32x16_bf16(vf0, pf.v, oacc[0], 0, 0, 0);
      oacc[1] = __builtin_amdgcn_mfma_f32_32x32x16_bf16(vf1, pf.v, oacc[1], 0, 0, 0);
      lacc = __builtin_amdgcn_mfma_f32_32x32x16_bf16(ones.v, pf.v, lacc, 0, 0, 0);
      __builtin_amdgcn_s_setprio(0);
    }
    if (t < 31) __syncthreads();  // drains gloads (vmcnt) + buffer handoff
  }
  const float l_run = lacc[0];

  // ---- epilogue: memory retrieval + gated injection (fused gate) ----
  float den = 0.f;
  bf16x8 cqf[4];
  const float* nrm = mnorm + (size_t)(b * NHEAD + n) * 64;
#pragma unroll
  for (int ks = 0; ks < 4; ++ks) {
    u16x8 qv = *(const u16x8*)(qkv + qoff + ks * 16 + h * 8);
    union { u16x8 u; bf16x8 v; } cu;
#pragma unroll
    for (int e = 0; e < 8; ++e) {
      float x = bf2f(qv[e]);
      float c = (x > 0.f) ? (x + 1.f) : __builtin_amdgcn_exp2f(x * 1.4426950408889634f);
      cu.u[e] = f2bf(c);
      den += c * nrm[ks * 16 + h * 8 + e];
    }
    cqf[ks] = cu.v;
  }
  den += __shfl_xor(den, 32);

  const float* mb = mem + (size_t)(b * NHEAD + n) * 4096;
  f32x16 accv[2];
#pragma unroll
  for (int r = 0; r < 16; ++r) { accv[0][r] = 0.f; accv[1][r] = 0.f; }
#pragma unroll
  for (int db = 0; db < 2; ++db)
#pragma unroll
    for (int ks = 0; ks < 4; ++ks) {
      union { u16x8 u; bf16x8 v; } af;
#pragma unroll
      for (int e = 0; e < 8; ++e)
        af.u[e] = f2bf(mb[(size_t)(ks * 16 + h * 8 + e) * 64 + db * 32 + l31]);
      accv[db] = __builtin_amdgcn_mfma_f32_32x32x16_bf16(af.v, cqf[ks], accv[db], 0, 0, 0);
    }

  float g = 1.f / (1.f + expf(-gbeta[0]));
  float rden = 1.f / den, invl = 1.f / l_run;
  ushort_t* op = inj + (size_t)qrow * 2048 + b * 1024 + n * 64;
#pragma unroll
  for (int db = 0; db < 2; ++db)
#pragma unroll
    for (int qq = 0; qq < 4; ++qq) {
      u16x4 st;
#pragma unroll
      for (int m = 0; m < 4; ++m) {
        float content = accv[db][qq * 4 + m] * rden;
        float av = oacc[db][qq * 4 + m] * invl;
        st[m] = f2bf(g * content + (1.f - g) * av);
      }
      *(u16x4*)(op + db * 32 + qq * 8 + h * 4) = st;
    }
}

// ------------- y = h + attn_out; LayerNorm(D=1024) -------------
__global__ __launch_bounds__(256) void k_ln(const float* __restrict__ h,
                                            const float* __restrict__ ao,
                                            const float* __restrict__ gam,
                                            const float* __restrict__ bet,
                                            float* __restrict__ out) {
  const int m = blockIdx.x, t = threadIdx.x;
  const int lane = t & 63, w = t >> 6;
  __shared__ float redS[4], redQ[4];
  const size_t base = (size_t)m * 1024;
  float4 hv = ((const float4*)(h + base))[t];
  float4 avv = ((const float4*)(ao + base))[t];
  float y0 = hv.x + avv.x, y1 = hv.y + avv.y, y2 = hv.z + avv.z, y3 = hv.w + avv.w;
  float s = y0 + y1 + y2 + y3;
  float sq = y0 * y0 + y1 * y1 + y2 * y2 + y3 * y3;
#pragma unroll
  for (int mk = 32; mk >= 1; mk >>= 1) { s += __shfl_xor(s, mk); sq += __shfl_xor(sq, mk); }
  if (lane == 0) { redS[w] = s; redQ[w] = sq; }
  __syncthreads();
  float Ssum = redS[0] + redS[1] + redS[2] + redS[3];
  float Qsum = redQ[0] + redQ[1] + redQ[2] + redQ[3];
  float mu = Ssum * (1.f / 1024.f);
  float var = Qsum * (1.f / 1024.f) - mu * mu;
  float rstd = rsqrtf(var + 1e-5f);
  float4 g = ((const float4*)gam)[t];
  float4 bt = ((const float4*)bet)[t];
  float4 o;
  o.x = (y0 - mu) * rstd * g.x + bt.x;
  o.y = (y1 - mu) * rstd * g.y + bt.y;
  o.z = (y2 - mu) * rstd * g.z + bt.z;
  o.w = (y3 - mu) * rstd * g.w + bt.w;
  ((float4*)(out + base))[t] = o;
}

extern "C" void kernel_launch(void* const* d_in, const int* in_sizes, int n_in,
                              void* d_out, int out_size, void* d_ws, size_t ws_size,
                              hipStream_t stream) {
  const float* h = (const float*)d_in[0];
  const float* Wq = (const float*)d_in[1];
  const float* Wkv = (const float*)d_in[2];
  const float* Wo = (const float*)d_in[3];
  const float* gam = (const float*)d_in[4];
  const float* bet = (const float*)d_in[5];
  const float* mem = (const float*)d_in[6];
  const float* mnorm = (const float*)d_in[7];
  const float* gbeta = (const float*)d_in[8];
  float* out = (float*)d_out;

  char* ws = (char*)d_ws;
  // [0,8M) hb (reused as inj) | [8M,14M) wT | [14M,16M) woT |
  // [16M,40M) qkv (reused as ao fp32) | [40M,48M) vt
  ushort_t* hb  = (ushort_t*)(ws);
  ushort_t* wT  = (ushort_t*)(ws + (size_t)(8u << 20));
  ushort_t* woT = (ushort_t*)(ws + (size_t)(14u << 20));
  ushort_t* qkv = (ushort_t*)(ws + (size_t)(16u << 20));
  float*    ao  = (float*)   (ws + (size_t)(16u << 20));  // alias qkv (dead by then)
  ushort_t* vtb = (ushort_t*)(ws + (size_t)(40u << 20));
  ushort_t* inj = hb;                                     // alias hb (dead by then)

  k_cvt_h<<<4096, 256, 0, stream>>>(h, hb, 1048576);
  k_cvt_wT<<<dim3(32, 32), 256, 0, stream>>>(Wq, wT, 1024, 1024);
  k_cvt_wT<<<dim3(64, 32), 256, 0, stream>>>(Wkv, wT + (size_t)1024 * 1024, 1024, 2048);
  k_cvt_wT<<<dim3(32, 32), 256, 0, stream>>>(Wo, woT, 1024, 1024);
  k_gemm_bt<1><<<768, 256, 0, stream>>>(hb, wT, (void*)qkv, 4096, 3072, 1024, 24);
  k_vt<<<dim3(32, 32), 256, 0, stream>>>(qkv, vtb);
  k_attn<<<dim3(16, 32), 256, 0, stream>>>(qkv, vtb, mem, mnorm, gbeta, inj);
  k_gemm64<<<512, 256, 0, stream>>>(inj, woT, ao, 4096, 1024, 1024, 8);
  k_ln<<<4096, 256, 0, stream>>>(h, ao, gam, bet, out);
}

// Round 8
// 145.023 us; speedup vs baseline: 1.2053x; 1.0054x over previous
//
#include <hip/hip_runtime.h>

// InfiniAttn forward on gfx950.
// cvt h->bf16 | transpose W->bf16 (merged x3) | GEMM qkv | V-transpose | fused flash attn
// + mem-gate (256-thr, fixed-max softmax, prescaled Q, K & V^T staged via global_load_lds
// with pre-swizzled source, 3-stage pipeline with COUNTED vmcnt + raw barriers,
// l via ones-MFMA) | GEMM out 64x128 | +h,LN.

typedef unsigned short ushort_t;
typedef unsigned int uint32;

typedef __bf16 bf16x8 __attribute__((ext_vector_type(8)));
typedef float f32x4 __attribute__((ext_vector_type(4)));
typedef float f32x16 __attribute__((ext_vector_type(16)));
typedef unsigned short u16x8 __attribute__((ext_vector_type(8)));
typedef unsigned short u16x4 __attribute__((ext_vector_type(4)));
typedef unsigned int u32x4 __attribute__((ext_vector_type(4)));

typedef const __attribute__((address_space(1))) void gvoid_t;
typedef __attribute__((address_space(3))) void lvoid_t;

#define S_LEN 2048
#define BATCH 2
#define NHEAD 16

__device__ __forceinline__ ushort_t f2bf(float x) {
  union { float f; unsigned u; } c; c.f = x;
  unsigned r = (c.u + 0x7FFFu + ((c.u >> 16) & 1u)) >> 16;
  return (ushort_t)r;
}
__device__ __forceinline__ float bf2f(ushort_t v) {
  union { unsigned u; float f; } c; c.u = ((unsigned)v) << 16;
  return c.f;
}

// ---------------- dtype convert: h (fp32) -> bf16 ----------------
__global__ __launch_bounds__(256) void k_cvt_h(const float* __restrict__ src,
                                               ushort_t* __restrict__ dst, int n4) {
  int idx = blockIdx.x * 256 + threadIdx.x;
  if (idx >= n4) return;
  float4 v = ((const float4*)src)[idx];
  u16x4 o; o[0] = f2bf(v.x); o[1] = f2bf(v.y); o[2] = f2bf(v.z); o[3] = f2bf(v.w);
  ((u16x4*)dst)[idx] = o;
}

// ------------- transpose-convert (merged): W[K][N] fp32 -> WT[N][K] bf16 -------------
__global__ __launch_bounds__(256) void k_cvt_wT3(const float* __restrict__ Wq,
                                                 const float* __restrict__ Wkv,
                                                 const float* __restrict__ Wo,
                                                 ushort_t* __restrict__ wT,
                                                 ushort_t* __restrict__ woT) {
  const int z = blockIdx.z;
  const float* W;
  ushort_t* WT;
  int N;
  if (z == 0)      { W = Wq;  WT = wT;                          N = 1024; }
  else if (z == 1) { W = Wkv; WT = wT + (size_t)1024 * 1024;    N = 2048; }
  else             { W = Wo;  WT = woT;                         N = 1024; }
  const int K = 1024;
  if (blockIdx.x * 32 >= N) return;
  __shared__ float tile[32][33];
  const int n0 = blockIdx.x * 32, k0 = blockIdx.y * 32;
  const int tx = threadIdx.x & 31, ty = threadIdx.x >> 5;
#pragma unroll
  for (int r = 0; r < 32; r += 8)
    tile[ty + r][tx] = W[(size_t)(k0 + ty + r) * N + n0 + tx];
  __syncthreads();
#pragma unroll
  for (int r = 0; r < 32; r += 8)
    WT[(size_t)(n0 + ty + r) * K + k0 + tx] = f2bf(tile[tx][ty + r]);
}

// ------------- GEMM 128x128: C = A[M][K](bf16) * B[N][K]^T(bf16), m97-style + XCD swizzle -------------
template <int OUT_BF16>
__global__ __launch_bounds__(256) void k_gemm_bt(const ushort_t* __restrict__ A,
                                                 const ushort_t* __restrict__ B,
                                                 void* __restrict__ Cv, int M, int N, int K,
                                                 int nbx) {
  __shared__ __attribute__((aligned(16))) ushort_t As[128 * 32];
  __shared__ __attribute__((aligned(16))) ushort_t Bs[128 * 32];
  const int per = gridDim.x >> 3;  // grid % 8 == 0
  const int fl = (blockIdx.x & 7) * per + (blockIdx.x >> 3);
  const int m0 = (fl / nbx) * 128, n0 = (fl % nbx) * 128;
  const int tid = threadIdx.x, w = tid >> 6, lane = tid & 63;
  const int wm = (w >> 1) * 64, wn = (w & 1) * 64;
  const int l15 = lane & 15, l4 = lane >> 4;
  f32x4 acc[4][4];
#pragma unroll
  for (int i = 0; i < 4; ++i)
#pragma unroll
    for (int j = 0; j < 4; ++j)
#pragma unroll
      for (int r = 0; r < 4; ++r) acc[i][j][r] = 0.f;

  for (int k0 = 0; k0 < K; k0 += 32) {
    __syncthreads();
#pragma unroll
    for (int r = 0; r < 2; ++r) {
      int c = r * 256 + w * 64 + lane;
      const ushort_t* ga = A + (size_t)(m0 + (c >> 2)) * K + k0 + (c & 3) * 8;
      const ushort_t* gb = B + (size_t)(n0 + (c >> 2)) * K + k0 + (c & 3) * 8;
      __builtin_amdgcn_global_load_lds((gvoid_t*)ga, (lvoid_t*)(As + (r * 256 + w * 64) * 8), 16, 0, 0);
      __builtin_amdgcn_global_load_lds((gvoid_t*)gb, (lvoid_t*)(Bs + (r * 256 + w * 64) * 8), 16, 0, 0);
    }
    __syncthreads();
    bf16x8 af[4], bfr[4];
#pragma unroll
    for (int i = 0; i < 4; ++i) af[i] = *(const bf16x8*)&As[(wm + i * 16 + l15) * 32 + l4 * 8];
#pragma unroll
    for (int j = 0; j < 4; ++j) bfr[j] = *(const bf16x8*)&Bs[(wn + j * 16 + l15) * 32 + l4 * 8];
#pragma unroll
    for (int i = 0; i < 4; ++i)
#pragma unroll
      for (int j = 0; j < 4; ++j)
        acc[i][j] = __builtin_amdgcn_mfma_f32_16x16x32_bf16(af[i], bfr[j], acc[i][j], 0, 0, 0);
  }
#pragma unroll
  for (int i = 0; i < 4; ++i)
#pragma unroll
    for (int j = 0; j < 4; ++j)
#pragma unroll
      for (int r = 0; r < 4; ++r) {
        int row = m0 + wm + i * 16 + l4 * 4 + r;
        int col = n0 + wn + j * 16 + l15;
        if (OUT_BF16)
          ((ushort_t*)Cv)[(size_t)row * N + col] = f2bf(acc[i][j][r]);
        else
          ((float*)Cv)[(size_t)row * N + col] = acc[i][j][r];
      }
}

// ------------- GEMM 64x128 tiles (for M=4096,N=1024: 512 blocks = 2/CU) -------------
__global__ __launch_bounds__(256) void k_gemm64(const ushort_t* __restrict__ A,
                                                const ushort_t* __restrict__ B,
                                                float* __restrict__ C, int M, int N, int K,
                                                int nbx) {
  __shared__ __attribute__((aligned(16))) ushort_t As[64 * 32];
  __shared__ __attribute__((aligned(16))) ushort_t Bs[128 * 32];
  const int per = gridDim.x >> 3;
  const int fl = (blockIdx.x & 7) * per + (blockIdx.x >> 3);
  const int m0 = (fl / nbx) * 64, n0 = (fl % nbx) * 128;
  const int tid = threadIdx.x, w = tid >> 6, lane = tid & 63;
  const int wn = w * 32;
  const int l15 = lane & 15, l4 = lane >> 4;
  f32x4 acc[4][2];
#pragma unroll
  for (int i = 0; i < 4; ++i)
#pragma unroll
    for (int j = 0; j < 2; ++j)
#pragma unroll
      for (int r = 0; r < 4; ++r) acc[i][j][r] = 0.f;

  for (int k0 = 0; k0 < K; k0 += 32) {
    __syncthreads();
    {
      int c = w * 64 + lane;
      const ushort_t* ga = A + (size_t)(m0 + (c >> 2)) * K + k0 + (c & 3) * 8;
      __builtin_amdgcn_global_load_lds((gvoid_t*)ga, (lvoid_t*)(As + w * 512), 16, 0, 0);
#pragma unroll
      for (int r = 0; r < 2; ++r) {
        int c2 = r * 256 + w * 64 + lane;
        const ushort_t* gb = B + (size_t)(n0 + (c2 >> 2)) * K + k0 + (c2 & 3) * 8;
        __builtin_amdgcn_global_load_lds((gvoid_t*)gb, (lvoid_t*)(Bs + r * 2048 + w * 512), 16, 0, 0);
      }
    }
    __syncthreads();
    bf16x8 af[4], bfr[2];
#pragma unroll
    for (int i = 0; i < 4; ++i) af[i] = *(const bf16x8*)&As[(i * 16 + l15) * 32 + l4 * 8];
#pragma unroll
    for (int j = 0; j < 2; ++j) bfr[j] = *(const bf16x8*)&Bs[(wn + j * 16 + l15) * 32 + l4 * 8];
#pragma unroll
    for (int i = 0; i < 4; ++i)
#pragma unroll
      for (int j = 0; j < 2; ++j)
        acc[i][j] = __builtin_amdgcn_mfma_f32_16x16x32_bf16(af[i], bfr[j], acc[i][j], 0, 0, 0);
  }
#pragma unroll
  for (int i = 0; i < 4; ++i)
#pragma unroll
    for (int j = 0; j < 2; ++j)
#pragma unroll
      for (int r = 0; r < 4; ++r)
        C[(size_t)(m0 + i * 16 + l4 * 4 + r) * N + n0 + wn + j * 16 + l15] = acc[i][j][r];
}

// ------------- V transpose: qkv V-part -> VT[bn][d][j] (bf16), once per (b,n) -------------
__global__ __launch_bounds__(256) void k_vt(const ushort_t* __restrict__ qkv,
                                            ushort_t* __restrict__ vt) {
  __shared__ uint32 tile[64 * 65];
  const int jt = blockIdx.x, bn = blockIdx.y, b = bn & 1, n = bn >> 1;
  const int tid = threadIdx.x;
  const int j0 = jt * 64;
#pragma unroll
  for (int rr = 0; rr < 2; ++rr) {
    int lin = rr * 2048 + tid * 8;
    int j = lin >> 6, d0 = lin & 63;
    u16x8 v = *(const u16x8*)(qkv + (size_t)(j0 + j) * 6144 + b * 3072 + 2048 + n * 64 + d0);
#pragma unroll
    for (int e = 0; e < 8; ++e) tile[j * 65 + d0 + e] = v[e];
  }
  __syncthreads();
#pragma unroll
  for (int rr = 0; rr < 2; ++rr) {
    int lin = rr * 2048 + tid * 8;
    int d = lin >> 6, jj = lin & 63;
    u16x8 o;
#pragma unroll
    for (int e = 0; e < 8; ++e) o[e] = (ushort_t)tile[(jj + e) * 65 + d];
    *(u16x8*)(vt + ((size_t)bn * 64 + d) * 2048 + j0 + jj) = o;
  }
}

// ------------- staging: global_load_lds with pre-swizzled source -------------
// LDS layout [64 rows][8 slots x 8 shorts]; LDS[row][s] = src[row][s ^ g(row)],
// g(row) = (row&7) ^ ((row>>3)&7).  Per call rows jb_..jb_+7: (row>>3) = jb8 const.
__device__ __forceinline__ void stage_k(const ushort_t* __restrict__ qkv, ushort_t* kw,
                                        int j0, int b, int n, int w, int lane) {
#pragma unroll
  for (int r = 0; r < 2; ++r) {
    int jb_ = w * 16 + r * 8;
    int jb8 = w * 2 + r;
    const ushort_t* ksrc = qkv + (size_t)(j0 + jb_ + (lane >> 3)) * 6144 + b * 3072 + n * 64 + 1024
                           + ((((lane & 7) ^ (lane >> 3) ^ jb8) & 7) << 3);
    __builtin_amdgcn_global_load_lds((gvoid_t*)ksrc, (lvoid_t*)(kw + jb_ * 64), 16, 0, 0);
  }
}
__device__ __forceinline__ void stage_vt(const ushort_t* __restrict__ vt, ushort_t* vw,
                                         int j0, int bn, int w, int lane) {
#pragma unroll
  for (int r = 0; r < 2; ++r) {
    int db_ = w * 16 + r * 8;
    int jb8 = w * 2 + r;
    const ushort_t* vsrc = vt + ((size_t)bn * 64 + db_ + (lane >> 3)) * 2048 + j0
                           + ((((lane & 7) ^ (lane >> 3) ^ jb8) & 7) << 3);
    __builtin_amdgcn_global_load_lds((gvoid_t*)vsrc, (lvoid_t*)(vw + db_ * 64), 16, 0, 0);
  }
}

// ------------- fused flash attention + memory gate (256 thr, fixed-max) -------------
// 3-stage pipeline, counted vmcnt (never 0 in steady state) + raw s_barrier (T3/T4).
// Per tile per wave: 4 VMEM ops. Steady: after issuing t+2, outstanding <= 12;
// vmcnt(8) waits tile t's 4 only. Overwrite safety: stage at iter t targets the
// buffer read at t-1, protected by t-1's trailing barrier.
__global__ __launch_bounds__(256) void k_attn(const ushort_t* __restrict__ qkv,
                                              const ushort_t* __restrict__ vt,
                                              const float* __restrict__ mem,
                                              const float* __restrict__ mnorm,
                                              const float* __restrict__ gbeta,
                                              ushort_t* __restrict__ inj) {
  __shared__ __attribute__((aligned(16))) ushort_t Ks[3][4096];
  __shared__ __attribute__((aligned(16))) ushort_t VTs[3][4096];
  const int bn = blockIdx.y, b = bn & 1, n = bn >> 1;
  const int tid = threadIdx.x, w = tid >> 6, lane = tid & 63;
  const int l31 = lane & 31, h = lane >> 5;
  const int qrow = blockIdx.x * 128 + w * 32 + l31;
  const size_t qoff = (size_t)qrow * 6144 + b * 3072 + n * 64;
  const float CEXP = 0.18033688011113723f;  // 0.125 * log2(e)
  // prescaled Q fragments
  bf16x8 qf[4];
#pragma unroll
  for (int ks = 0; ks < 4; ++ks) {
    u16x8 qv = *(const u16x8*)(qkv + qoff + ks * 16 + h * 8);
    union { u16x8 u; bf16x8 v; } cu;
#pragma unroll
    for (int e = 0; e < 8; ++e) cu.u[e] = f2bf(bf2f(qv[e]) * CEXP);
    qf[ks] = cu.v;
  }
  const int fA = (l31 & 7) ^ (l31 >> 3);  // read swizzle rows 0-31; rows 32-63: fA^4
  const int fB = fA ^ 4;
  union { u16x8 u; bf16x8 v; } ones;
#pragma unroll
  for (int e = 0; e < 8; ++e) ones.u[e] = 0x3F80;  // bf16 1.0

  // ---- prologue: stage tiles 0 and 1 (8 VMEM ops in flight) ----
  stage_k(qkv, Ks[0], 0, b, n, w, lane);
  stage_vt(vt, VTs[0], 0, bn, w, lane);
  stage_k(qkv, Ks[1], 64, b, n, w, lane);
  stage_vt(vt, VTs[1], 64, bn, w, lane);

  f32x16 oacc[2], lacc;
#pragma unroll
  for (int r = 0; r < 16; ++r) { oacc[0][r] = 0.f; oacc[1][r] = 0.f; lacc[r] = 0.f; }

  int cur = 0, stg = 2;
  for (int t = 0; t < 32; ++t) {
    if (t + 2 < 32) {  // issue prefetch for tile t+2
      stage_k(qkv, Ks[stg], (t + 2) * 64, b, n, w, lane);
      stage_vt(vt, VTs[stg], (t + 2) * 64, bn, w, lane);
    }
    // counted wait: tile t's loads done; t+1/t+2's stay in flight
    if (t < 30)       asm volatile("s_waitcnt vmcnt(8)" ::: "memory");
    else if (t == 30) asm volatile("s_waitcnt vmcnt(4)" ::: "memory");
    else              asm volatile("s_waitcnt vmcnt(0)" ::: "memory");
    __builtin_amdgcn_s_barrier();

    const ushort_t* Kb = Ks[cur];
    const ushort_t* Vb = VTs[cur];
    // S^T = mfma(A=K, B=Q): lane holds S[own q=l31][j = jb*32 + (r&3)+8*(r>>2)+4h]
    f32x16 sv[2];
#pragma unroll
    for (int r = 0; r < 16; ++r) { sv[0][r] = 0.f; sv[1][r] = 0.f; }
    __builtin_amdgcn_s_setprio(1);
#pragma unroll
    for (int jb = 0; jb < 2; ++jb) {
      const int rb = (jb * 32 + l31) * 64;
      const int fj = jb ? fB : fA;
#pragma unroll
      for (int ks = 0; ks < 4; ++ks) {
        bf16x8 kf = *(const bf16x8*)&Kb[rb + ((((ks << 1) | h) ^ fj) << 3)];
        sv[jb] = __builtin_amdgcn_mfma_f32_32x32x16_bf16(kf, qf[ks], sv[jb], 0, 0, 0);
      }
    }
    __builtin_amdgcn_s_setprio(0);
    // fixed-max softmax: p = exp2(sv) in place
#pragma unroll
    for (int jb = 0; jb < 2; ++jb)
#pragma unroll
      for (int r = 0; r < 16; ++r)
        sv[jb][r] = __builtin_amdgcn_exp2f(sv[jb][r]);
    // PV: O^T = mfma(A=V^T, B=P^T); P-frags via cvt_pk + permlane32_swap (T12).
    // l = sum_j P via ones-MFMA.
#pragma unroll
    for (int ks = 0; ks < 4; ++ks) {
      const int jb = ks >> 1, q0 = (ks & 1) * 2;
      uint32 X0, X1, Y0, Y1;
      asm volatile("v_cvt_pk_bf16_f32 %0, %1, %2" : "=v"(X0) : "v"(sv[jb][q0 * 4 + 0]), "v"(sv[jb][q0 * 4 + 1]));
      asm volatile("v_cvt_pk_bf16_f32 %0, %1, %2" : "=v"(X1) : "v"(sv[jb][q0 * 4 + 2]), "v"(sv[jb][q0 * 4 + 3]));
      asm volatile("v_cvt_pk_bf16_f32 %0, %1, %2" : "=v"(Y0) : "v"(sv[jb][(q0 + 1) * 4 + 0]), "v"(sv[jb][(q0 + 1) * 4 + 1]));
      asm volatile("v_cvt_pk_bf16_f32 %0, %1, %2" : "=v"(Y1) : "v"(sv[jb][(q0 + 1) * 4 + 2]), "v"(sv[jb][(q0 + 1) * 4 + 3]));
      asm volatile("v_permlane32_swap_b32 %0, %1" : "+v"(X0), "+v"(Y0));
      asm volatile("v_permlane32_swap_b32 %0, %1" : "+v"(X1), "+v"(Y1));
      union { u32x4 u; bf16x8 v; } pf;
      pf.u[0] = X0; pf.u[1] = X1; pf.u[2] = Y0; pf.u[3] = Y1;
      const int c = (ks << 1) | h;
      bf16x8 vf0 = *(const bf16x8*)&Vb[l31 * 64 + ((c ^ fA) << 3)];
      bf16x8 vf1 = *(const bf16x8*)&Vb[(32 + l31) * 64 + ((c ^ fB) << 3)];
      __builtin_amdgcn_s_setprio(1);
      oacc[0] = __builtin_amdgcn_mfma_f32_32x32x16_bf16(vf0, pf.v, oacc[0], 0, 0, 0);
      oacc[1] = __builtin_amdgcn_mfma_f32_32x32x16_bf16(vf1, pf.v, oacc[1], 0, 0, 0);
      lacc = __builtin_amdgcn_mfma_f32_32x32x16_bf16(ones.v, pf.v, lacc, 0, 0, 0);
      __builtin_amdgcn_s_setprio(0);
    }
    __builtin_amdgcn_s_barrier();  // reads done before next iter's overwrite issue
    cur = (cur + 1 == 3) ? 0 : cur + 1;
    stg = (stg + 1 == 3) ? 0 : stg + 1;
  }
  const float l_run = lacc[0];

  // ---- epilogue: memory retrieval + gated injection (fused gate) ----
  float den = 0.f;
  bf16x8 cqf[4];
  const float* nrm = mnorm + (size_t)(b * NHEAD + n) * 64;
#pragma unroll
  for (int ks = 0; ks < 4; ++ks) {
    u16x8 qv = *(const u16x8*)(qkv + qoff + ks * 16 + h * 8);
    union { u16x8 u; bf16x8 v; } cu;
#pragma unroll
    for (int e = 0; e < 8; ++e) {
      float x = bf2f(qv[e]);
      float c = (x > 0.f) ? (x + 1.f) : __builtin_amdgcn_exp2f(x * 1.4426950408889634f);
      cu.u[e] = f2bf(c);
      den += c * nrm[ks * 16 + h * 8 + e];
    }
    cqf[ks] = cu.v;
  }
  den += __shfl_xor(den, 32);

  const float* mb = mem + (size_t)(b * NHEAD + n) * 4096;
  f32x16 accv[2];
#pragma unroll
  for (int r = 0; r < 16; ++r) { accv[0][r] = 0.f; accv[1][r] = 0.f; }
#pragma unroll
  for (int db = 0; db < 2; ++db)
#pragma unroll
    for (int ks = 0; ks < 4; ++ks) {
      union { u16x8 u; bf16x8 v; } af;
#pragma unroll
      for (int e = 0; e < 8; ++e)
        af.u[e] = f2bf(mb[(size_t)(ks * 16 + h * 8 + e) * 64 + db * 32 + l31]);
      accv[db] = __builtin_amdgcn_mfma_f32_32x32x16_bf16(af.v, cqf[ks], accv[db], 0, 0, 0);
    }

  float g = 1.f / (1.f + expf(-gbeta[0]));
  float rden = 1.f / den, invl = 1.f / l_run;
  ushort_t* op = inj + (size_t)qrow * 2048 + b * 1024 + n * 64;
#pragma unroll
  for (int db = 0; db < 2; ++db)
#pragma unroll
    for (int qq = 0; qq < 4; ++qq) {
      u16x4 st;
#pragma unroll
      for (int m = 0; m < 4; ++m) {
        float content = accv[db][qq * 4 + m] * rden;
        float av = oacc[db][qq * 4 + m] * invl;
        st[m] = f2bf(g * content + (1.f - g) * av);
      }
      *(u16x4*)(op + db * 32 + qq * 8 + h * 4) = st;
    }
}

// ------------- y = h + attn_out; LayerNorm(D=1024) -------------
__global__ __launch_bounds__(256) void k_ln(const float* __restrict__ h,
                                            const float* __restrict__ ao,
                                            const float* __restrict__ gam,
                                            const float* __restrict__ bet,
                                            float* __restrict__ out) {
  const int m = blockIdx.x, t = threadIdx.x;
  const int lane = t & 63, w = t >> 6;
  __shared__ float redS[4], redQ[4];
  const size_t base = (size_t)m * 1024;
  float4 hv = ((const float4*)(h + base))[t];
  float4 avv = ((const float4*)(ao + base))[t];
  float y0 = hv.x + avv.x, y1 = hv.y + avv.y, y2 = hv.z + avv.z, y3 = hv.w + avv.w;
  float s = y0 + y1 + y2 + y3;
  float sq = y0 * y0 + y1 * y1 + y2 * y2 + y3 * y3;
#pragma unroll
  for (int mk = 32; mk >= 1; mk >>= 1) { s += __shfl_xor(s, mk); sq += __shfl_xor(sq, mk); }
  if (lane == 0) { redS[w] = s; redQ[w] = sq; }
  __syncthreads();
  float Ssum = redS[0] + redS[1] + redS[2] + redS[3];
  float Qsum = redQ[0] + redQ[1] + redQ[2] + redQ[3];
  float mu = Ssum * (1.f / 1024.f);
  float var = Qsum * (1.f / 1024.f) - mu * mu;
  float rstd = rsqrtf(var + 1e-5f);
  float4 g = ((const float4*)gam)[t];
  float4 bt = ((const float4*)bet)[t];
  float4 o;
  o.x = (y0 - mu) * rstd * g.x + bt.x;
  o.y = (y1 - mu) * rstd * g.y + bt.y;
  o.z = (y2 - mu) * rstd * g.z + bt.z;
  o.w = (y3 - mu) * rstd * g.w + bt.w;
  ((float4*)(out + base))[t] = o;
}

extern "C" void kernel_launch(void* const* d_in, const int* in_sizes, int n_in,
                              void* d_out, int out_size, void* d_ws, size_t ws_size,
                              hipStream_t stream) {
  const float* h = (const float*)d_in[0];
  const float* Wq = (const float*)d_in[1];
  const float* Wkv = (const float*)d_in[2];
  const float* Wo = (const float*)d_in[3];
  const float* gam = (const float*)d_in[4];
  const float* bet = (const float*)d_in[5];
  const float* mem = (const float*)d_in[6];
  const float* mnorm = (const float*)d_in[7];
  const float* gbeta = (const float*)d_in[8];
  float* out = (float*)d_out;

  char* ws = (char*)d_ws;
  // [0,8M) hb (reused as inj) | [8M,14M) wT | [14M,16M) woT |
  // [16M,40M) qkv (reused as ao fp32) | [40M,48M) vt
  ushort_t* hb  = (ushort_t*)(ws);
  ushort_t* wT  = (ushort_t*)(ws + (size_t)(8u << 20));
  ushort_t* woT = (ushort_t*)(ws + (size_t)(14u << 20));
  ushort_t* qkv = (ushort_t*)(ws + (size_t)(16u << 20));
  float*    ao  = (float*)   (ws + (size_t)(16u << 20));  // alias qkv (dead by then)
  ushort_t* vtb = (ushort_t*)(ws + (size_t)(40u << 20));
  ushort_t* inj = hb;                                     // alias hb (dead by then)

  k_cvt_h<<<4096, 256, 0, stream>>>(h, hb, 1048576);
  k_cvt_wT3<<<dim3(64, 32, 3), 256, 0, stream>>>(Wq, Wkv, Wo, wT, woT);
  k_gemm_bt<1><<<768, 256, 0, stream>>>(hb, wT, (void*)qkv, 4096, 3072, 1024, 24);
  k_vt<<<dim3(32, 32), 256, 0, stream>>>(qkv, vtb);
  k_attn<<<dim3(16, 32), 256, 0, stream>>>(qkv, vtb, mem, mnorm, gbeta, inj);
  k_gemm64<<<512, 256, 0, stream>>>(inj, woT, ao, 4096, 1024, 1024, 8);
  k_ln<<<4096, 256, 0, stream>>>(h, ao, gam, bet, out);
}